// Round 1
// 582.787 us; speedup vs baseline: 1.2214x; 1.2214x over previous
//
#include <hip/hip_runtime.h>
#include <math.h>

#define T_LEN 1024
#define C_DIM 2048
#define H_N   32
#define HEAD  64
#define BTC   (T_LEN * C_DIM)
#define REC   384   // packed floats per (t,h): [d 64][a 64][b 64][k 64][v 64][r 64]
#define RKV_N 6144  // fused r|k|v GEMM output width

typedef __attribute__((ext_vector_type(8))) __bf16 bf16x8;
typedef __attribute__((ext_vector_type(4))) float  f32x4;

// ---------------- async global->LDS helper (16B/lane, wave-uniform LDS base) -------------
__device__ __forceinline__ void gll16(const void* g, void* l) {
    __builtin_amdgcn_global_load_lds((const __attribute__((address_space(1))) void*)g,
                                     (__attribute__((address_space(3))) void*)l, 16, 0, 0);
}

// 16-lane reduce, pure DPP: quad xor1, quad xor2, row_half_mirror (8), row_mirror (16)
__device__ __forceinline__ float hex_add(float x) {
    int a = __builtin_amdgcn_mov_dpp(__float_as_int(x), 0xB1, 0xF, 0xF, true);   // quad_perm [1,0,3,2]
    float y = x + __int_as_float(a);
    int b = __builtin_amdgcn_mov_dpp(__float_as_int(y), 0x4E, 0xF, 0xF, true);   // quad_perm [2,3,0,1]
    float z = y + __int_as_float(b);
    int c = __builtin_amdgcn_mov_dpp(__float_as_int(z), 0x141, 0xF, 0xF, true);  // row_half_mirror
    float w = z + __int_as_float(c);
    int d = __builtin_amdgcn_mov_dpp(__float_as_int(w), 0x140, 0xF, 0xF, true);  // row_mirror
    return w + __int_as_float(d);
}

// ---------------- elementwise cast kernels ----------------
__global__ void cast_bf16_k(const float* __restrict__ s, __bf16* __restrict__ d, int n) {
    int i = blockIdx.x * 256 + threadIdx.x;
    if (i < n) d[i] = (__bf16)s[i];
}
__global__ void tanh_cast_k(const float* __restrict__ s, __bf16* __restrict__ d, int n) {
    int i = blockIdx.x * 256 + threadIdx.x;
    if (i < n) d[i] = (__bf16)tanhf(s[i]);
}

// ---------------- transpose + cast: dst[c*R + r] = (bf16)src[r*C + c] ----------------
__global__ void transpose_cast_k(const float* __restrict__ src, __bf16* __restrict__ dst,
                                 int R, int C) {
    __shared__ float tile[32][33];
    int c0 = blockIdx.x * 32, r0 = blockIdx.y * 32;
    int tx = threadIdx.x, ty = threadIdx.y;
#pragma unroll
    for (int i = 0; i < 32; i += 8)
        tile[ty + i][tx] = src[(size_t)(r0 + ty + i) * C + c0 + tx];
    __syncthreads();
#pragma unroll
    for (int i = 0; i < 32; i += 8)
        dst[(size_t)(c0 + ty + i) * R + r0 + tx] = (__bf16)tile[tx][ty + i];
}

// ---------------- GEMM 64x128 tile, LDS-DMA staging: O = A(MxK) * BT(NxK) ----------------
// block 256 = 4 waves; wave computes 32x64 (2x4 MFMA tiles). 3 DMA + 8 MFMA + 6 ds_read/iter.
__global__ __launch_bounds__(256) void gemm_lds_64x128(
    const __bf16* __restrict__ A, const __bf16* __restrict__ BT,
    float* __restrict__ O, int M, int N, int K) {
    __shared__ __bf16 As[64 * 32];
    __shared__ __bf16 Bs[128 * 32];
    int tid  = threadIdx.x;
    int lane = tid & 63;
    int wv   = tid >> 6;
    int m    = lane & 15;
    int q    = lane >> 4;
    int wr   = wv >> 1, wc = wv & 1;
    int row0 = blockIdx.x * 64;
    int col0 = blockIdx.y * 128;

    int srow  = tid >> 2;          // 0..63
    int skoff = (tid & 3) * 8;
    const __bf16* agp = A  + (size_t)(row0 + srow) * K + skoff;
    const __bf16* bgp = BT + (size_t)(col0 + srow) * K + skoff;
    __bf16* alp = As + (size_t)(tid & ~63) * 8;   // wave-uniform base (+ HW lane*16B)
    __bf16* blp = Bs + (size_t)(tid & ~63) * 8;

    f32x4 acc[2][4];
#pragma unroll
    for (int i = 0; i < 2; i++)
#pragma unroll
        for (int j = 0; j < 4; j++) acc[i][j] = {0.f, 0.f, 0.f, 0.f};

    for (int k0 = 0; k0 < K; k0 += 32) {
        gll16(agp + k0, alp);
        gll16(bgp + k0, blp);
        gll16(bgp + (size_t)64 * K + k0, blp + 64 * 32);
        __syncthreads();

        bf16x8 af[2], bfv[4];
#pragma unroll
        for (int i = 0; i < 2; i++)
            af[i] = *(const bf16x8*)&As[(wr * 32 + i * 16 + m) * 32 + q * 8];
#pragma unroll
        for (int j = 0; j < 4; j++)
            bfv[j] = *(const bf16x8*)&Bs[(wc * 64 + j * 16 + m) * 32 + q * 8];
#pragma unroll
        for (int i = 0; i < 2; i++)
#pragma unroll
            for (int j = 0; j < 4; j++)
                acc[i][j] = __builtin_amdgcn_mfma_f32_16x16x32_bf16(af[i], bfv[j], acc[i][j], 0, 0, 0);
        __syncthreads();
    }

#pragma unroll
    for (int i = 0; i < 2; i++) {
        int orow = row0 + wr * 32 + i * 16 + q * 4;
#pragma unroll
        for (int j = 0; j < 4; j++) {
            int ocol = col0 + wc * 64 + j * 16 + m;
#pragma unroll
            for (int t = 0; t < 4; t++)
                O[(size_t)(orow + t) * N + ocol] = acc[i][j][t];
        }
    }
}

// ---------------- small GEMM: one wave per 16x16 tile (LoRA stage 1) ----------------
__global__ __launch_bounds__(64) void gemm_bt_w16(
    const __bf16* __restrict__ A, const __bf16* __restrict__ BT,
    float* __restrict__ O, int M, int N, int K) {
    int lane = threadIdx.x & 63;
    int m = lane & 15, q = lane >> 4;
    int row0 = blockIdx.x * 16;
    int col0 = blockIdx.y * 16;
    const __bf16* ap = A  + (size_t)(row0 + m) * K + q * 8;
    const __bf16* bp = BT + (size_t)(col0 + m) * K + q * 8;
    f32x4 acc = {0.f,0.f,0.f,0.f};
    for (int k0 = 0; k0 < K; k0 += 32) {
        bf16x8 av = *(const bf16x8*)(ap + k0);
        bf16x8 bv = *(const bf16x8*)(bp + k0);
        acc = __builtin_amdgcn_mfma_f32_16x16x32_bf16(av, bv, acc, 0, 0, 0);
    }
    int orow = row0 + q * 4;
    int ocol = col0 + m;
#pragma unroll
    for (int i = 0; i < 4; i++)
        O[(size_t)(orow + i) * N + ocol] = acc[i];
}

// ---------------- prep: decay / gates / kk-normalize + mask folding + packing ----------------
// rkv layout: [t][0:2048)=r, [2048:4096)=k, [4096:6144)=v (stride RKV_N)
__global__ __launch_bounds__(64) void prep_k(
    float* __restrict__ rkv,
    const float* __restrict__ vfirst,
    const float* __restrict__ ywb, const float* __restrict__ yab,
    const float* __restrict__ yvb,
    float* __restrict__ pk,
    const float* __restrict__ w0, const float* __restrict__ a0,
    const float* __restrict__ v0, const float* __restrict__ k_k,
    const float* __restrict__ k_a, const float* __restrict__ amask) {
    int t = blockIdx.x >> 5;
    int h = blockIdx.x & 31;
    int n = threadIdx.x;
    int cc   = h * HEAD + n;
    int idx  = t * C_DIM + cc;          // for ywb/yab/yvb/vfirst
    size_t idx6 = (size_t)t * RKV_N + cc;
    float m = amask[t];

    float rr = rkv[idx6];
    float kv = rkv[idx6 + 2048];
    float vv = rkv[idx6 + 4096];
    float wv = w0[cc] + ywb[idx];
    float wfin = -log1pf(expf(-wv)) - 0.6f;       // -softplus(-x) - 0.6
    float dec  = expf(-expf(wfin));
    float sv   = 1.f / (1.f + expf(-(v0[cc] + yvb[idx])));
    float vnew = fmaf(vfirst[idx] - vv, sv, vv);
    float av   = 1.f / (1.f + expf(-(a0[cc] + yab[idx])));
    float kkp  = kv * k_k[cc];
    float ss = kkp * kkp;
#pragma unroll
    for (int off = 32; off > 0; off >>= 1) ss += __shfl_xor(ss, off);
    float kkn  = kkp / fmaxf(sqrtf(ss), 1e-12f);
    float knew = kv * (1.f + (av - 1.f) * k_a[cc]);

    size_t rec = ((size_t)t * H_N + h) * REC;
    pk[rec + n]       = dec * m + (1.f - m);   // d_eff
    pk[rec + 64 + n]  = -kkn * m;              // a_eff
    pk[rec + 128 + n] = kkn * av * m;          // b_eff
    pk[rec + 192 + n] = knew * m;              // k_eff
    pk[rec + 256 + n] = vnew * m;              // v_eff
    pk[rec + 320 + n] = rr;                    // r (unmasked)
    rkv[idx6 + 2048] = knew;                   // unmasked, for residual
    rkv[idx6 + 4096] = vnew;                   // unmasked, for residual
}

// ---------------- sequential scan v2: register-ring-8 direct global loads -----------------
// 512 single-wave blocks (2/CU). block = (head h, row-quarter g); lane = r*16+c holds
// S[g*4+r][c*4..c*4+4). Inputs stream straight into VGPRs (5x dwordx4 + 1 dword per lane
// per step), depth-8 ring statically indexed via 8-unrolled inner loop; compiler inserts
// counted vmcnt waits from register deps. No LDS, no lgkmcnt round-trip on the chain.
__global__ __launch_bounds__(64, 1) void scan_k(
    const float* __restrict__ pk, float* __restrict__ out) {
    int b = blockIdx.x;
    int xcd  = b & 7;
    int rest = b >> 3;       // 0..63
    int hi   = rest & 3;
    int g    = rest >> 2;    // 0..15
    int h    = xcd + 8 * hi;

    int lane = threadIdx.x;
    int r = lane >> 4;       // 0..3
    int c = lane & 15;       // 0..15
    int row = g * 4 + r;
    int jb  = c * 4;

    float S0 = 0.f, S1 = 0.f, S2 = 0.f, S3 = 0.f;

    float4 dR[8], aR[8], bR[8], kR[8], rR[8];
    float  vR[8];

    const size_t tstep = (size_t)H_N * REC;   // 12288 floats per timestep
    const float* base = pk + (size_t)h * REC;

#define LOADSLOT(S_, T_) do {                          \
    const float* L_ = base + (size_t)(T_) * tstep;     \
    dR[S_] = *(const float4*)(L_ + jb);                \
    aR[S_] = *(const float4*)(L_ + 64 + jb);           \
    bR[S_] = *(const float4*)(L_ + 128 + jb);          \
    kR[S_] = *(const float4*)(L_ + 192 + jb);          \
    vR[S_] = L_[256 + row];                            \
    rR[S_] = *(const float4*)(L_ + 320 + jb);          \
} while (0)

#pragma unroll
    for (int s = 0; s < 8; ++s) LOADSLOT(s, s);

    int off = h * HEAD;

#pragma unroll 1
    for (int t0 = 0; t0 < T_LEN; t0 += 8) {
#pragma unroll
        for (int s = 0; s < 8; ++s) {
            int t = t0 + s;
            float4 dv = dR[s], av = aR[s], bv = bR[s], kv = kR[s], rv = rR[s];
            float  vv = vR[s];
            // prefetch t+8 into this slot (issues early; compiler tracks deps)
            int tn = t + 8;
            if (tn > T_LEN - 1) tn = T_LEN - 1;
            LOADSLOT(s, tn);
            // S . a  (reduce over 16 lanes = 16 columns-of-4)
            float p0 = fmaf(S0, av.x, S1 * av.y);
            float p1 = fmaf(S2, av.z, S3 * av.w);
            float sa = hex_add(p0 + p1);
            // state update: S = S*d + sa*b + v*k
            float u0 = fmaf(sa, bv.x, vv * kv.x);
            float u1 = fmaf(sa, bv.y, vv * kv.y);
            float u2 = fmaf(sa, bv.z, vv * kv.z);
            float u3 = fmaf(sa, bv.w, vv * kv.w);
            S0 = fmaf(dv.x, S0, u0);
            S1 = fmaf(dv.y, S1, u1);
            S2 = fmaf(dv.z, S2, u2);
            S3 = fmaf(dv.w, S3, u3);
            // out = S . r  (off the recurrence critical path)
            float o0 = fmaf(S0, rv.x, S1 * rv.y);
            float o1 = fmaf(S2, rv.z, S3 * rv.w);
            float op = hex_add(o0 + o1);
            if (c == 0) out[off + row] = op;
            off += C_DIM;
        }
    }
#undef LOADSLOT
}

// ---------------- residual + cast + v_first passthrough ----------------
__global__ __launch_bounds__(64) void resid_k(
    const float* __restrict__ rkv, const float* __restrict__ souts,
    const float* __restrict__ r_k, const float* __restrict__ vfirst,
    __bf16* __restrict__ ob, float* __restrict__ dout) {
    int t = blockIdx.x >> 5;
    int h = blockIdx.x & 31;
    int n = threadIdx.x;
    int cc  = h * HEAD + n;
    int idx = t * C_DIM + cc;
    size_t idx6 = (size_t)t * RKV_N + cc;
    float s = rkv[idx6] * rkv[idx6 + 2048] * r_k[cc];
#pragma unroll
    for (int off = 32; off > 0; off >>= 1) s += __shfl_xor(s, off);
    float ov = souts[idx] + s * rkv[idx6 + 4096];
    ob[idx] = (__bf16)ov;
    dout[BTC + idx] = vfirst[idx];
}

// ---------------- host launcher ----------------
extern "C" void kernel_launch(void* const* d_in, const int* in_sizes, int n_in,
                              void* d_out, int out_size, void* d_ws, size_t ws_size,
                              hipStream_t stream) {
    const float* x      = (const float*)d_in[0];
    const float* vfirst = (const float*)d_in[1];
    const float* amask  = (const float*)d_in[2];
    const float* w0 = (const float*)d_in[3];
    const float* w1 = (const float*)d_in[4];
    const float* w2 = (const float*)d_in[5];
    const float* a0 = (const float*)d_in[6];
    const float* a1 = (const float*)d_in[7];
    const float* a2 = (const float*)d_in[8];
    const float* v0 = (const float*)d_in[9];
    const float* v1 = (const float*)d_in[10];
    const float* v2 = (const float*)d_in[11];
    const float* k_k = (const float*)d_in[12];
    const float* k_a = (const float*)d_in[13];
    const float* r_k = (const float*)d_in[14];
    const float* Wr = (const float*)d_in[15];
    const float* Wk = (const float*)d_in[16];
    const float* Wv = (const float*)d_in[17];
    const float* Wo = (const float*)d_in[18];
    float* dout = (float*)d_out;

    char* wp = (char*)d_ws;
    auto alloc = [&](size_t bytes) -> void* {
        void* p = (void*)wp;
        wp += (bytes + 255) & ~(size_t)255;
        return p;
    };
    __bf16* xb   = (__bf16*)alloc((size_t)BTC * 2);
    __bf16* rkvT = (__bf16*)alloc((size_t)3 * C_DIM * C_DIM * 2);  // WrT|WkT|WvT contiguous
    __bf16* WoT  = (__bf16*)alloc((size_t)C_DIM * C_DIM * 2);
    __bf16* w1T = (__bf16*)alloc((size_t)96 * C_DIM * 2);
    __bf16* a1T = (__bf16*)alloc((size_t)96 * C_DIM * 2);
    __bf16* v1T = (__bf16*)alloc((size_t)64 * C_DIM * 2);
    __bf16* w2T = (__bf16*)alloc((size_t)C_DIM * 96 * 2);
    __bf16* a2T = (__bf16*)alloc((size_t)C_DIM * 96 * 2);
    __bf16* v2T = (__bf16*)alloc((size_t)C_DIM * 64 * 2);
    float*  rkv = (float*)alloc((size_t)T_LEN * RKV_N * 4);        // fused r|k|v output
    float*  hw  = (float*)alloc((size_t)T_LEN * 96 * 4);
    float*  ha  = (float*)alloc((size_t)T_LEN * 96 * 4);
    float*  hv  = (float*)alloc((size_t)T_LEN * 64 * 4);
    __bf16* hwb = (__bf16*)alloc((size_t)T_LEN * 96 * 2);
    __bf16* hab = (__bf16*)alloc((size_t)T_LEN * 96 * 2);
    __bf16* hvb = (__bf16*)alloc((size_t)T_LEN * 64 * 2);
    float*  ywb = (float*)alloc((size_t)BTC * 4);   // LoRA w output
    float*  yab = (float*)alloc((size_t)BTC * 4);   // LoRA a output
    float*  yvb = (float*)alloc((size_t)BTC * 4);   // LoRA v output
    float*  pk  = (float*)alloc((size_t)T_LEN * H_N * REC * 4 + 4096);
    float*  souts = (float*)alloc((size_t)BTC * 4);
    __bf16* ob  = (__bf16*)alloc((size_t)BTC * 2);

    // 1) cast x -> bf16
    cast_bf16_k<<<dim3(BTC / 256), 256, 0, stream>>>(x, xb, BTC);

    // 2) transpose+cast all weights (dst = C x R); Wr/Wk/Wv into one contiguous BT
    dim3 tb(32, 8);
    transpose_cast_k<<<dim3(64, 64), tb, 0, stream>>>(Wr, rkvT, C_DIM, C_DIM);
    transpose_cast_k<<<dim3(64, 64), tb, 0, stream>>>(Wk, rkvT + (size_t)C_DIM * C_DIM, C_DIM, C_DIM);
    transpose_cast_k<<<dim3(64, 64), tb, 0, stream>>>(Wv, rkvT + (size_t)2 * C_DIM * C_DIM, C_DIM, C_DIM);
    transpose_cast_k<<<dim3(64, 64), tb, 0, stream>>>(Wo, WoT, C_DIM, C_DIM);
    transpose_cast_k<<<dim3(3, 64), tb, 0, stream>>>(w1, w1T, C_DIM, 96);
    transpose_cast_k<<<dim3(3, 64), tb, 0, stream>>>(a1, a1T, C_DIM, 96);
    transpose_cast_k<<<dim3(2, 64), tb, 0, stream>>>(v1, v1T, C_DIM, 64);
    transpose_cast_k<<<dim3(64, 3), tb, 0, stream>>>(w2, w2T, 96, C_DIM);
    transpose_cast_k<<<dim3(64, 3), tb, 0, stream>>>(a2, a2T, 96, C_DIM);
    transpose_cast_k<<<dim3(64, 2), tb, 0, stream>>>(v2, v2T, 64, C_DIM);

    // 3) fused big GEMM: rkv = xb @ [Wr|Wk|Wv]  (768 blocks = 3/CU)
    gemm_lds_64x128<<<dim3(16, 48), 256, 0, stream>>>(xb, rkvT, rkv, T_LEN, RKV_N, C_DIM);

    // 4) LoRA first stage
    gemm_bt_w16<<<dim3(64, 6), 64, 0, stream>>>(xb, w1T, hw, T_LEN, 96, C_DIM);
    gemm_bt_w16<<<dim3(64, 6), 64, 0, stream>>>(xb, a1T, ha, T_LEN, 96, C_DIM);
    gemm_bt_w16<<<dim3(64, 4), 64, 0, stream>>>(xb, v1T, hv, T_LEN, 64, C_DIM);

    // 5) activations + cast
    tanh_cast_k<<<dim3((T_LEN * 96 + 255) / 256), 256, 0, stream>>>(hw, hwb, T_LEN * 96);
    cast_bf16_k<<<dim3((T_LEN * 96 + 255) / 256), 256, 0, stream>>>(ha, hab, T_LEN * 96);
    cast_bf16_k<<<dim3((T_LEN * 64 + 255) / 256), 256, 0, stream>>>(hv, hvb, T_LEN * 64);

    // 6) LoRA second stage (64x128 tiles, 256 blocks)
    gemm_lds_64x128<<<dim3(16, 16), 256, 0, stream>>>(hwb, w2T, ywb, T_LEN, C_DIM, 96);
    gemm_lds_64x128<<<dim3(16, 16), 256, 0, stream>>>(hab, a2T, yab, T_LEN, C_DIM, 96);
    gemm_lds_64x128<<<dim3(16, 16), 256, 0, stream>>>(hvb, v2T, yvb, T_LEN, C_DIM, 64);

    // 7) prep: decay, gates, kk-normalize, mask folding, record packing
    prep_k<<<dim3(T_LEN * H_N), 64, 0, stream>>>(rkv, vfirst, ywb, yab, yvb,
                                                 pk, w0, a0, v0, k_k, k_a, amask);

    // 8) sequential scan v2: 512 blocks x 1 wave (2/CU), DPP hex-reduce, register-ring-8
    scan_k<<<dim3(H_N * 16), 64, 0, stream>>>(pk, souts);

    // 9) residual + cast + v_first passthrough
    resid_k<<<dim3(T_LEN * H_N), 64, 0, stream>>>(rkv, souts, r_k, vfirst, ob, dout);

    // 10) final GEMM: dout[0:BTC] = ob @ Wo
    gemm_lds_64x128<<<dim3(16, 16), 256, 0, stream>>>(ob, WoT, dout, T_LEN, C_DIM, C_DIM);
}

// Round 2
// 528.492 us; speedup vs baseline: 1.3469x; 1.1027x over previous
//
#include <hip/hip_runtime.h>
#include <math.h>

#define T_LEN 1024
#define C_DIM 2048
#define H_N   32
#define HEAD  64
#define BTC   (T_LEN * C_DIM)
#define REC2  768   // packed floats per (t-pair,h): [A1|A2|R1|DD|B1|B2|C1|C2|R2|v1|v2|G1+pad] x64
#define RKV_N 6144  // fused r|k|v GEMM output width

typedef __attribute__((ext_vector_type(8))) __bf16 bf16x8;
typedef __attribute__((ext_vector_type(4))) float  f32x4;

// ---------------- async global->LDS helper (16B/lane, wave-uniform LDS base) -------------
__device__ __forceinline__ void gll16(const void* g, void* l) {
    __builtin_amdgcn_global_load_lds((const __attribute__((address_space(1))) void*)g,
                                     (__attribute__((address_space(3))) void*)l, 16, 0, 0);
}

// 16-lane reduce, pure DPP: quad xor1, quad xor2, row_half_mirror (8), row_mirror (16)
__device__ __forceinline__ float hex_add(float x) {
    int a = __builtin_amdgcn_mov_dpp(__float_as_int(x), 0xB1, 0xF, 0xF, true);   // quad_perm [1,0,3,2]
    float y = x + __int_as_float(a);
    int b = __builtin_amdgcn_mov_dpp(__float_as_int(y), 0x4E, 0xF, 0xF, true);   // quad_perm [2,3,0,1]
    float z = y + __int_as_float(b);
    int c = __builtin_amdgcn_mov_dpp(__float_as_int(z), 0x141, 0xF, 0xF, true);  // row_half_mirror
    float w = z + __int_as_float(c);
    int d = __builtin_amdgcn_mov_dpp(__float_as_int(w), 0x140, 0xF, 0xF, true);  // row_mirror
    return w + __int_as_float(d);
}

// ---------------- elementwise cast kernels ----------------
__global__ void cast_bf16_k(const float* __restrict__ s, __bf16* __restrict__ d, int n) {
    int i = blockIdx.x * 256 + threadIdx.x;
    if (i < n) d[i] = (__bf16)s[i];
}
__global__ void tanh_cast_k(const float* __restrict__ s, __bf16* __restrict__ d, int n) {
    int i = blockIdx.x * 256 + threadIdx.x;
    if (i < n) d[i] = (__bf16)tanhf(s[i]);
}

// ---------------- transpose + cast: dst[c*R + r] = (bf16)src[r*C + c] ----------------
__global__ void transpose_cast_k(const float* __restrict__ src, __bf16* __restrict__ dst,
                                 int R, int C) {
    __shared__ float tile[32][33];
    int c0 = blockIdx.x * 32, r0 = blockIdx.y * 32;
    int tx = threadIdx.x, ty = threadIdx.y;
#pragma unroll
    for (int i = 0; i < 32; i += 8)
        tile[ty + i][tx] = src[(size_t)(r0 + ty + i) * C + c0 + tx];
    __syncthreads();
#pragma unroll
    for (int i = 0; i < 32; i += 8)
        dst[(size_t)(c0 + ty + i) * R + r0 + tx] = (__bf16)tile[tx][ty + i];
}

// ---------------- GEMM 64x128 tile, LDS-DMA staging: O = A(MxK) * BT(NxK) ----------------
// block 256 = 4 waves; wave computes 32x64 (2x4 MFMA tiles). 3 DMA + 8 MFMA + 6 ds_read/iter.
__global__ __launch_bounds__(256) void gemm_lds_64x128(
    const __bf16* __restrict__ A, const __bf16* __restrict__ BT,
    float* __restrict__ O, int M, int N, int K) {
    __shared__ __bf16 As[64 * 32];
    __shared__ __bf16 Bs[128 * 32];
    int tid  = threadIdx.x;
    int lane = tid & 63;
    int wv   = tid >> 6;
    int m    = lane & 15;
    int q    = lane >> 4;
    int wr   = wv >> 1, wc = wv & 1;
    int row0 = blockIdx.x * 64;
    int col0 = blockIdx.y * 128;

    int srow  = tid >> 2;          // 0..63
    int skoff = (tid & 3) * 8;
    const __bf16* agp = A  + (size_t)(row0 + srow) * K + skoff;
    const __bf16* bgp = BT + (size_t)(col0 + srow) * K + skoff;
    __bf16* alp = As + (size_t)(tid & ~63) * 8;   // wave-uniform base (+ HW lane*16B)
    __bf16* blp = Bs + (size_t)(tid & ~63) * 8;

    f32x4 acc[2][4];
#pragma unroll
    for (int i = 0; i < 2; i++)
#pragma unroll
        for (int j = 0; j < 4; j++) acc[i][j] = {0.f, 0.f, 0.f, 0.f};

    for (int k0 = 0; k0 < K; k0 += 32) {
        gll16(agp + k0, alp);
        gll16(bgp + k0, blp);
        gll16(bgp + (size_t)64 * K + k0, blp + 64 * 32);
        __syncthreads();

        bf16x8 af[2], bfv[4];
#pragma unroll
        for (int i = 0; i < 2; i++)
            af[i] = *(const bf16x8*)&As[(wr * 32 + i * 16 + m) * 32 + q * 8];
#pragma unroll
        for (int j = 0; j < 4; j++)
            bfv[j] = *(const bf16x8*)&Bs[(wc * 64 + j * 16 + m) * 32 + q * 8];
#pragma unroll
        for (int i = 0; i < 2; i++)
#pragma unroll
            for (int j = 0; j < 4; j++)
                acc[i][j] = __builtin_amdgcn_mfma_f32_16x16x32_bf16(af[i], bfv[j], acc[i][j], 0, 0, 0);
        __syncthreads();
    }

#pragma unroll
    for (int i = 0; i < 2; i++) {
        int orow = row0 + wr * 32 + i * 16 + q * 4;
#pragma unroll
        for (int j = 0; j < 4; j++) {
            int ocol = col0 + wc * 64 + j * 16 + m;
#pragma unroll
            for (int t = 0; t < 4; t++)
                O[(size_t)(orow + t) * N + ocol] = acc[i][j][t];
        }
    }
}

// ---------------- small GEMM: one wave per 16x16 tile (LoRA stage 1) ----------------
__global__ __launch_bounds__(64) void gemm_bt_w16(
    const __bf16* __restrict__ A, const __bf16* __restrict__ BT,
    float* __restrict__ O, int M, int N, int K) {
    int lane = threadIdx.x & 63;
    int m = lane & 15, q = lane >> 4;
    int row0 = blockIdx.x * 16;
    int col0 = blockIdx.y * 16;
    const __bf16* ap = A  + (size_t)(row0 + m) * K + q * 8;
    const __bf16* bp = BT + (size_t)(col0 + m) * K + q * 8;
    f32x4 acc = {0.f,0.f,0.f,0.f};
    for (int k0 = 0; k0 < K; k0 += 32) {
        bf16x8 av = *(const bf16x8*)(ap + k0);
        bf16x8 bv = *(const bf16x8*)(bp + k0);
        acc = __builtin_amdgcn_mfma_f32_16x16x32_bf16(av, bv, acc, 0, 0, 0);
    }
    int orow = row0 + q * 4;
    int ocol = col0 + m;
#pragma unroll
    for (int i = 0; i < 4; i++)
        O[(size_t)(orow + i) * N + ocol] = acc[i];
}

// ---------------- prep2: per t-PAIR, compute gates + compose two recurrence steps --------
// Single step: S_t = S_{t-1} M_t + v_t k_t^T, M = diag(d) + a b^T.
// Double step:  S   = S*DD + (S.A1) B1 + (S.A2) B2 + v1 C1 + v2 C2
//   DD = d1*d2; A1 = a1; B1 = d2*b1 + (b1.a2) b2; A2 = d1*a2; B2 = b2;
//   C1 = d2*k1 + (k1.a2) b2; C2 = k2.
// Intermediate output: out_t = S_{t-1}.R1 + (k1.r1) v1, R1 = d1*r1 + (b1.r1) a1.
// rkv layout: [t][0:2048)=r, [2048:4096)=k, [4096:6144)=v (stride RKV_N)
__global__ __launch_bounds__(64) void prep2_k(
    float* __restrict__ rkv,
    const float* __restrict__ vfirst,
    const float* __restrict__ ywb, const float* __restrict__ yab,
    const float* __restrict__ yvb,
    float* __restrict__ pk,
    const float* __restrict__ w0, const float* __restrict__ a0,
    const float* __restrict__ v0, const float* __restrict__ k_k,
    const float* __restrict__ k_a, const float* __restrict__ amask) {
    int tp = blockIdx.x >> 5;
    int h  = blockIdx.x & 31;
    int n  = threadIdx.x;
    int cc = h * HEAD + n;

    float d[2], a[2], bv[2], k[2], v[2], r[2];
#pragma unroll
    for (int s = 0; s < 2; ++s) {
        int t = 2 * tp + s;
        int idx = t * C_DIM + cc;
        size_t idx6 = (size_t)t * RKV_N + cc;
        float m  = amask[t];
        float rr = rkv[idx6];
        float kv = rkv[idx6 + 2048];
        float vv = rkv[idx6 + 4096];
        float wv = w0[cc] + ywb[idx];
        float wfin = -log1pf(expf(-wv)) - 0.6f;       // -softplus(-x) - 0.6
        float dec  = expf(-expf(wfin));
        float sv   = 1.f / (1.f + expf(-(v0[cc] + yvb[idx])));
        float vnew = fmaf(vfirst[idx] - vv, sv, vv);
        float av   = 1.f / (1.f + expf(-(a0[cc] + yab[idx])));
        float kkp  = kv * k_k[cc];
        float ss = kkp * kkp;
#pragma unroll
        for (int off = 32; off > 0; off >>= 1) ss += __shfl_xor(ss, off);
        float kkn  = kkp / fmaxf(sqrtf(ss), 1e-12f);
        float knew = kv * (1.f + (av - 1.f) * k_a[cc]);
        d[s]  = dec * m + (1.f - m);
        a[s]  = -kkn * m;
        bv[s] = kkn * av * m;
        k[s]  = knew * m;
        v[s]  = vnew * m;
        r[s]  = rr;
        rkv[idx6 + 2048] = knew;   // unmasked, for residual
        rkv[idx6 + 4096] = vnew;   // unmasked, for residual
    }

    // cross-step dot products (64-lane reduces)
    float dba = bv[0] * a[1];   // b1.a2
    float dka = k[0]  * a[1];   // k1.a2
    float dbr = bv[0] * r[0];   // b1.r1
    float dkr = k[0]  * r[0];   // k1.r1
#pragma unroll
    for (int off = 32; off > 0; off >>= 1) {
        dba += __shfl_xor(dba, off);
        dka += __shfl_xor(dka, off);
        dbr += __shfl_xor(dbr, off);
        dkr += __shfl_xor(dkr, off);
    }

    size_t rec = ((size_t)tp * H_N + h) * REC2;
    pk[rec + n]        = a[0];                          // A1
    pk[rec + 64 + n]   = d[0] * a[1];                   // A2
    pk[rec + 128 + n]  = fmaf(dbr, a[0], d[0] * r[0]);  // R1
    pk[rec + 192 + n]  = d[0] * d[1];                   // DD
    pk[rec + 256 + n]  = fmaf(dba, bv[1], d[1] * bv[0]);// B1
    pk[rec + 320 + n]  = bv[1];                         // B2
    pk[rec + 384 + n]  = fmaf(dka, bv[1], d[1] * k[0]); // C1
    pk[rec + 448 + n]  = k[1];                          // C2
    pk[rec + 512 + n]  = r[1];                          // R2
    pk[rec + 576 + n]  = v[0];                          // v1
    pk[rec + 640 + n]  = v[1];                          // v2
    if (n == 0) pk[rec + 704] = dkr;                    // G1 scalar
}

// ---------------- sequential scan v3: DOUBLE-STEP, register-ring-4 direct global loads ----
// 512 single-wave blocks (2/CU). block = (head h, row-quarter g); lane = r*16+c holds
// S[g*4+r][c*4..c*4+4). 512 composed steps; 3 parallel 16-lane DPP reduces per step
// (S.A1, S.A2, S.R1), then rank-2+diag update, then post-update reduce for out2.
__global__ __launch_bounds__(64, 1) void scan_k(
    const float* __restrict__ pk, float* __restrict__ out) {
    int b = blockIdx.x;
    int xcd  = b & 7;
    int rest = b >> 3;       // 0..63
    int hi   = rest & 3;
    int g    = rest >> 2;    // 0..15
    int h    = xcd + 8 * hi;

    int lane = threadIdx.x;
    int r = lane >> 4;       // 0..3
    int c = lane & 15;       // 0..15
    int row = g * 4 + r;
    int jb  = c * 4;

    float S0 = 0.f, S1 = 0.f, S2 = 0.f, S3 = 0.f;

    float4 A1R[4], A2R[4], R1R[4], DDR[4], B1R[4], B2R[4], C1R[4], C2R[4], R2R[4];
    float  v1R[4], v2R[4], g1R[4];

    const size_t tstep = (size_t)H_N * REC2;   // 24576 floats per t-pair
    const float* base = pk + (size_t)h * REC2;

#define LOADSLOT(S_, T_) do {                          \
    const float* L_ = base + (size_t)(T_) * tstep;     \
    A1R[S_] = *(const float4*)(L_ + jb);               \
    A2R[S_] = *(const float4*)(L_ + 64 + jb);          \
    R1R[S_] = *(const float4*)(L_ + 128 + jb);         \
    DDR[S_] = *(const float4*)(L_ + 192 + jb);         \
    B1R[S_] = *(const float4*)(L_ + 256 + jb);         \
    B2R[S_] = *(const float4*)(L_ + 320 + jb);         \
    C1R[S_] = *(const float4*)(L_ + 384 + jb);         \
    C2R[S_] = *(const float4*)(L_ + 448 + jb);         \
    R2R[S_] = *(const float4*)(L_ + 512 + jb);         \
    v1R[S_] = L_[576 + row];                           \
    v2R[S_] = L_[640 + row];                           \
    g1R[S_] = L_[704];                                 \
} while (0)

#pragma unroll
    for (int s = 0; s < 4; ++s) LOADSLOT(s, s);

    int off = h * HEAD;

#pragma unroll 1
    for (int tp0 = 0; tp0 < T_LEN / 2; tp0 += 4) {
#pragma unroll
        for (int s = 0; s < 4; ++s) {
            int tp = tp0 + s;
            float4 A1v = A1R[s], A2v = A2R[s], R1v = R1R[s], DDv = DDR[s];
            float4 B1v = B1R[s], B2v = B2R[s], C1v = C1R[s], C2v = C2R[s];
            float4 R2v = R2R[s];
            float  vv1 = v1R[s], vv2 = v2R[s], gg1 = g1R[s];
            // prefetch tp+4 into this slot
            int tn = tp + 4;
            if (tn > T_LEN / 2 - 1) tn = T_LEN / 2 - 1;
            LOADSLOT(s, tn);

            // three parallel 16-lane reduces on pre-update S
            float pa = fmaf(S0, A1v.x, S1 * A1v.y);
            float qa = fmaf(S2, A1v.z, S3 * A1v.w);
            float pb = fmaf(S0, A2v.x, S1 * A2v.y);
            float qb = fmaf(S2, A2v.z, S3 * A2v.w);
            float pr = fmaf(S0, R1v.x, S1 * R1v.y);
            float qr = fmaf(S2, R1v.z, S3 * R1v.w);
            float sa1 = hex_add(pa + qa);
            float sa2 = hex_add(pb + qb);
            float so1 = hex_add(pr + qr);
            // first output (timestep 2*tp)
            if (c == 0) out[off + row] = fmaf(gg1, vv1, so1);

            // const term (off critical path): v1*C1 + v2*C2
            float t0c = fmaf(vv1, C1v.x, vv2 * C2v.x);
            float t1c = fmaf(vv1, C1v.y, vv2 * C2v.y);
            float t2c = fmaf(vv1, C1v.z, vv2 * C2v.z);
            float t3c = fmaf(vv1, C1v.w, vv2 * C2v.w);
            // update: S = S*DD + sa1*B1 + sa2*B2 + const
            float z0 = fmaf(sa1, B1v.x, t0c);
            float z1 = fmaf(sa1, B1v.y, t1c);
            float z2 = fmaf(sa1, B1v.z, t2c);
            float z3 = fmaf(sa1, B1v.w, t3c);
            float y0 = fmaf(sa2, B2v.x, z0);
            float y1 = fmaf(sa2, B2v.y, z1);
            float y2 = fmaf(sa2, B2v.z, z2);
            float y3 = fmaf(sa2, B2v.w, z3);
            S0 = fmaf(DDv.x, S0, y0);
            S1 = fmaf(DDv.y, S1, y1);
            S2 = fmaf(DDv.z, S2, y2);
            S3 = fmaf(DDv.w, S3, y3);

            // second output (timestep 2*tp+1) on post-update S
            float o0 = fmaf(S0, R2v.x, S1 * R2v.y);
            float o1 = fmaf(S2, R2v.z, S3 * R2v.w);
            float op = hex_add(o0 + o1);
            if (c == 0) out[off + C_DIM + row] = op;
            off += 2 * C_DIM;
        }
    }
#undef LOADSLOT
}

// ---------------- residual + cast + v_first passthrough ----------------
__global__ __launch_bounds__(64) void resid_k(
    const float* __restrict__ rkv, const float* __restrict__ souts,
    const float* __restrict__ r_k, const float* __restrict__ vfirst,
    __bf16* __restrict__ ob, float* __restrict__ dout) {
    int t = blockIdx.x >> 5;
    int h = blockIdx.x & 31;
    int n = threadIdx.x;
    int cc  = h * HEAD + n;
    int idx = t * C_DIM + cc;
    size_t idx6 = (size_t)t * RKV_N + cc;
    float s = rkv[idx6] * rkv[idx6 + 2048] * r_k[cc];
#pragma unroll
    for (int off = 32; off > 0; off >>= 1) s += __shfl_xor(s, off);
    float ov = souts[idx] + s * rkv[idx6 + 4096];
    ob[idx] = (__bf16)ov;
    dout[BTC + idx] = vfirst[idx];
}

// ---------------- host launcher ----------------
extern "C" void kernel_launch(void* const* d_in, const int* in_sizes, int n_in,
                              void* d_out, int out_size, void* d_ws, size_t ws_size,
                              hipStream_t stream) {
    const float* x      = (const float*)d_in[0];
    const float* vfirst = (const float*)d_in[1];
    const float* amask  = (const float*)d_in[2];
    const float* w0 = (const float*)d_in[3];
    const float* w1 = (const float*)d_in[4];
    const float* w2 = (const float*)d_in[5];
    const float* a0 = (const float*)d_in[6];
    const float* a1 = (const float*)d_in[7];
    const float* a2 = (const float*)d_in[8];
    const float* v0 = (const float*)d_in[9];
    const float* v1 = (const float*)d_in[10];
    const float* v2 = (const float*)d_in[11];
    const float* k_k = (const float*)d_in[12];
    const float* k_a = (const float*)d_in[13];
    const float* r_k = (const float*)d_in[14];
    const float* Wr = (const float*)d_in[15];
    const float* Wk = (const float*)d_in[16];
    const float* Wv = (const float*)d_in[17];
    const float* Wo = (const float*)d_in[18];
    float* dout = (float*)d_out;

    char* wp = (char*)d_ws;
    auto alloc = [&](size_t bytes) -> void* {
        void* p = (void*)wp;
        wp += (bytes + 255) & ~(size_t)255;
        return p;
    };
    __bf16* xb   = (__bf16*)alloc((size_t)BTC * 2);
    __bf16* rkvT = (__bf16*)alloc((size_t)3 * C_DIM * C_DIM * 2);  // WrT|WkT|WvT contiguous
    __bf16* WoT  = (__bf16*)alloc((size_t)C_DIM * C_DIM * 2);
    __bf16* w1T = (__bf16*)alloc((size_t)96 * C_DIM * 2);
    __bf16* a1T = (__bf16*)alloc((size_t)96 * C_DIM * 2);
    __bf16* v1T = (__bf16*)alloc((size_t)64 * C_DIM * 2);
    __bf16* w2T = (__bf16*)alloc((size_t)C_DIM * 96 * 2);
    __bf16* a2T = (__bf16*)alloc((size_t)C_DIM * 96 * 2);
    __bf16* v2T = (__bf16*)alloc((size_t)C_DIM * 64 * 2);
    float*  rkv = (float*)alloc((size_t)T_LEN * RKV_N * 4);        // fused r|k|v output
    float*  hw  = (float*)alloc((size_t)T_LEN * 96 * 4);
    float*  ha  = (float*)alloc((size_t)T_LEN * 96 * 4);
    float*  hv  = (float*)alloc((size_t)T_LEN * 64 * 4);
    __bf16* hwb = (__bf16*)alloc((size_t)T_LEN * 96 * 2);
    __bf16* hab = (__bf16*)alloc((size_t)T_LEN * 96 * 2);
    __bf16* hvb = (__bf16*)alloc((size_t)T_LEN * 64 * 2);
    float*  ywb = (float*)alloc((size_t)BTC * 4);   // LoRA w output
    float*  yab = (float*)alloc((size_t)BTC * 4);   // LoRA a output
    float*  yvb = (float*)alloc((size_t)BTC * 4);   // LoRA v output
    float*  pk  = (float*)alloc((size_t)(T_LEN / 2) * H_N * REC2 * 4 + 4096);
    float*  souts = (float*)alloc((size_t)BTC * 4);
    __bf16* ob  = (__bf16*)alloc((size_t)BTC * 2);

    // 1) cast x -> bf16
    cast_bf16_k<<<dim3(BTC / 256), 256, 0, stream>>>(x, xb, BTC);

    // 2) transpose+cast all weights (dst = C x R); Wr/Wk/Wv into one contiguous BT
    dim3 tb(32, 8);
    transpose_cast_k<<<dim3(64, 64), tb, 0, stream>>>(Wr, rkvT, C_DIM, C_DIM);
    transpose_cast_k<<<dim3(64, 64), tb, 0, stream>>>(Wk, rkvT + (size_t)C_DIM * C_DIM, C_DIM, C_DIM);
    transpose_cast_k<<<dim3(64, 64), tb, 0, stream>>>(Wv, rkvT + (size_t)2 * C_DIM * C_DIM, C_DIM, C_DIM);
    transpose_cast_k<<<dim3(64, 64), tb, 0, stream>>>(Wo, WoT, C_DIM, C_DIM);
    transpose_cast_k<<<dim3(3, 64), tb, 0, stream>>>(w1, w1T, C_DIM, 96);
    transpose_cast_k<<<dim3(3, 64), tb, 0, stream>>>(a1, a1T, C_DIM, 96);
    transpose_cast_k<<<dim3(2, 64), tb, 0, stream>>>(v1, v1T, C_DIM, 64);
    transpose_cast_k<<<dim3(64, 3), tb, 0, stream>>>(w2, w2T, 96, C_DIM);
    transpose_cast_k<<<dim3(64, 3), tb, 0, stream>>>(a2, a2T, 96, C_DIM);
    transpose_cast_k<<<dim3(64, 2), tb, 0, stream>>>(v2, v2T, 64, C_DIM);

    // 3) fused big GEMM: rkv = xb @ [Wr|Wk|Wv]  (768 blocks = 3/CU)
    gemm_lds_64x128<<<dim3(16, 48), 256, 0, stream>>>(xb, rkvT, rkv, T_LEN, RKV_N, C_DIM);

    // 4) LoRA first stage
    gemm_bt_w16<<<dim3(64, 6), 64, 0, stream>>>(xb, w1T, hw, T_LEN, 96, C_DIM);
    gemm_bt_w16<<<dim3(64, 6), 64, 0, stream>>>(xb, a1T, ha, T_LEN, 96, C_DIM);
    gemm_bt_w16<<<dim3(64, 4), 64, 0, stream>>>(xb, v1T, hv, T_LEN, 64, C_DIM);

    // 5) activations + cast
    tanh_cast_k<<<dim3((T_LEN * 96 + 255) / 256), 256, 0, stream>>>(hw, hwb, T_LEN * 96);
    cast_bf16_k<<<dim3((T_LEN * 96 + 255) / 256), 256, 0, stream>>>(ha, hab, T_LEN * 96);
    cast_bf16_k<<<dim3((T_LEN * 64 + 255) / 256), 256, 0, stream>>>(hv, hvb, T_LEN * 64);

    // 6) LoRA second stage (64x128 tiles, 256 blocks)
    gemm_lds_64x128<<<dim3(16, 16), 256, 0, stream>>>(hwb, w2T, ywb, T_LEN, C_DIM, 96);
    gemm_lds_64x128<<<dim3(16, 16), 256, 0, stream>>>(hab, a2T, yab, T_LEN, C_DIM, 96);
    gemm_lds_64x128<<<dim3(16, 16), 256, 0, stream>>>(hvb, v2T, yvb, T_LEN, C_DIM, 64);

    // 7) prep2: decay, gates, kk-normalize, mask folding, TWO-STEP composition packing
    prep2_k<<<dim3((T_LEN / 2) * H_N), 64, 0, stream>>>(rkv, vfirst, ywb, yab, yvb,
                                                        pk, w0, a0, v0, k_k, k_a, amask);

    // 8) sequential scan v3: 512 blocks x 1 wave (2/CU), double-step, register-ring-4
    scan_k<<<dim3(H_N * 16), 64, 0, stream>>>(pk, souts);

    // 9) residual + cast + v_first passthrough
    resid_k<<<dim3(T_LEN * H_N), 64, 0, stream>>>(rkv, souts, r_k, vfirst, ob, dout);

    // 10) final GEMM: dout[0:BTC] = ob @ Wo
    gemm_lds_64x128<<<dim3(16, 16), 256, 0, stream>>>(ob, WoT, dout, T_LEN, C_DIM, C_DIM);
}

// Round 5
// 528.057 us; speedup vs baseline: 1.3480x; 1.0008x over previous
//
#include <hip/hip_runtime.h>
#include <math.h>

#define T_LEN 1024
#define C_DIM 2048
#define H_N   32
#define HEAD  64
#define BTC   (T_LEN * C_DIM)
#define REC2  768   // packed floats per (t-pair,h): [A1|A2|R1|DD|B1|B2|C1|C2|R2|v1|v2|G1+pad] x64
#define RKV_N 6144  // fused r|k|v GEMM output width
#define NPAIR (T_LEN / 2)

typedef __attribute__((ext_vector_type(8))) __bf16 bf16x8;
typedef __attribute__((ext_vector_type(4))) float  f32x4;

// ---------------- async global->LDS helper (16B/lane, wave-uniform LDS base) -------------
__device__ __forceinline__ void gll16(const void* g, void* l) {
    __builtin_amdgcn_global_load_lds((const __attribute__((address_space(1))) void*)g,
                                     (__attribute__((address_space(3))) void*)l, 16, 0, 0);
}

// 16-lane reduce, pure DPP: quad xor1, quad xor2, row_half_mirror (8), row_mirror (16)
__device__ __forceinline__ float hex_add(float x) {
    int a = __builtin_amdgcn_mov_dpp(__float_as_int(x), 0xB1, 0xF, 0xF, true);   // quad_perm [1,0,3,2]
    float y = x + __int_as_float(a);
    int b = __builtin_amdgcn_mov_dpp(__float_as_int(y), 0x4E, 0xF, 0xF, true);   // quad_perm [2,3,0,1]
    float z = y + __int_as_float(b);
    int c = __builtin_amdgcn_mov_dpp(__float_as_int(z), 0x141, 0xF, 0xF, true);  // row_half_mirror
    float w = z + __int_as_float(c);
    int d = __builtin_amdgcn_mov_dpp(__float_as_int(w), 0x140, 0xF, 0xF, true);  // row_mirror
    return w + __int_as_float(d);
}

// ---------------- elementwise cast kernels ----------------
__global__ void cast_bf16_k(const float* __restrict__ s, __bf16* __restrict__ d, int n) {
    int i = blockIdx.x * 256 + threadIdx.x;
    if (i < n) d[i] = (__bf16)s[i];
}
__global__ void tanh_cast_k(const float* __restrict__ s, __bf16* __restrict__ d, int n) {
    int i = blockIdx.x * 256 + threadIdx.x;
    if (i < n) d[i] = (__bf16)tanhf(s[i]);
}

// ---------------- transpose + cast: dst[c*R + r] = (bf16)src[r*C + c] ----------------
__global__ void transpose_cast_k(const float* __restrict__ src, __bf16* __restrict__ dst,
                                 int R, int C) {
    __shared__ float tile[32][33];
    int c0 = blockIdx.x * 32, r0 = blockIdx.y * 32;
    int tx = threadIdx.x, ty = threadIdx.y;
#pragma unroll
    for (int i = 0; i < 32; i += 8)
        tile[ty + i][tx] = src[(size_t)(r0 + ty + i) * C + c0 + tx];
    __syncthreads();
#pragma unroll
    for (int i = 0; i < 32; i += 8)
        dst[(size_t)(c0 + ty + i) * R + r0 + tx] = (__bf16)tile[tx][ty + i];
}

// ---------------- GEMM 64x128 tile, LDS-DMA staging: O = A(MxK) * BT(NxK) ----------------
__global__ __launch_bounds__(256) void gemm_lds_64x128(
    const __bf16* __restrict__ A, const __bf16* __restrict__ BT,
    float* __restrict__ O, int M, int N, int K) {
    __shared__ __bf16 As[64 * 32];
    __shared__ __bf16 Bs[128 * 32];
    int tid  = threadIdx.x;
    int lane = tid & 63;
    int wv   = tid >> 6;
    int m    = lane & 15;
    int q    = lane >> 4;
    int wr   = wv >> 1, wc = wv & 1;
    int row0 = blockIdx.x * 64;
    int col0 = blockIdx.y * 128;

    int srow  = tid >> 2;          // 0..63
    int skoff = (tid & 3) * 8;
    const __bf16* agp = A  + (size_t)(row0 + srow) * K + skoff;
    const __bf16* bgp = BT + (size_t)(col0 + srow) * K + skoff;
    __bf16* alp = As + (size_t)(tid & ~63) * 8;   // wave-uniform base (+ HW lane*16B)
    __bf16* blp = Bs + (size_t)(tid & ~63) * 8;

    f32x4 acc[2][4];
#pragma unroll
    for (int i = 0; i < 2; i++)
#pragma unroll
        for (int j = 0; j < 4; j++) acc[i][j] = {0.f, 0.f, 0.f, 0.f};

    for (int k0 = 0; k0 < K; k0 += 32) {
        gll16(agp + k0, alp);
        gll16(bgp + k0, blp);
        gll16(bgp + (size_t)64 * K + k0, blp + 64 * 32);
        __syncthreads();

        bf16x8 af[2], bfv[4];
#pragma unroll
        for (int i = 0; i < 2; i++)
            af[i] = *(const bf16x8*)&As[(wr * 32 + i * 16 + m) * 32 + q * 8];
#pragma unroll
        for (int j = 0; j < 4; j++)
            bfv[j] = *(const bf16x8*)&Bs[(wc * 64 + j * 16 + m) * 32 + q * 8];
#pragma unroll
        for (int i = 0; i < 2; i++)
#pragma unroll
            for (int j = 0; j < 4; j++)
                acc[i][j] = __builtin_amdgcn_mfma_f32_16x16x32_bf16(af[i], bfv[j], acc[i][j], 0, 0, 0);
        __syncthreads();
    }

#pragma unroll
    for (int i = 0; i < 2; i++) {
        int orow = row0 + wr * 32 + i * 16 + q * 4;
#pragma unroll
        for (int j = 0; j < 4; j++) {
            int ocol = col0 + wc * 64 + j * 16 + m;
#pragma unroll
            for (int t = 0; t < 4; t++)
                O[(size_t)(orow + t) * N + ocol] = acc[i][j][t];
        }
    }
}

// ---------------- small GEMM: one wave per 16x16 tile (LoRA stage 1) ----------------
__global__ __launch_bounds__(64) void gemm_bt_w16(
    const __bf16* __restrict__ A, const __bf16* __restrict__ BT,
    float* __restrict__ O, int M, int N, int K) {
    int lane = threadIdx.x & 63;
    int m = lane & 15, q = lane >> 4;
    int row0 = blockIdx.x * 16;
    int col0 = blockIdx.y * 16;
    const __bf16* ap = A  + (size_t)(row0 + m) * K + q * 8;
    const __bf16* bp = BT + (size_t)(col0 + m) * K + q * 8;
    f32x4 acc = {0.f,0.f,0.f,0.f};
    for (int k0 = 0; k0 < K; k0 += 32) {
        bf16x8 av = *(const bf16x8*)(ap + k0);
        bf16x8 bv = *(const bf16x8*)(bp + k0);
        acc = __builtin_amdgcn_mfma_f32_16x16x32_bf16(av, bv, acc, 0, 0, 0);
    }
    int orow = row0 + q * 4;
    int ocol = col0 + m;
#pragma unroll
    for (int i = 0; i < 4; i++)
        O[(size_t)(orow + i) * N + ocol] = acc[i];
}

// ---------------- prep2: per t-PAIR, compute gates + compose two recurrence steps --------
// Single step: S_t = S_{t-1} M_t + v_t k_t^T, M = diag(d) + a b^T.
// Double step:  S   = S*DD + (S.A1) B1 + (S.A2) B2 + v1 C1 + v2 C2
//   DD = d1*d2; A1 = a1; B1 = d2*b1 + (b1.a2) b2; A2 = d1*a2; B2 = b2;
//   C1 = d2*k1 + (k1.a2) b2; C2 = k2.
// Intermediate output: out_t = S_{t-1}.R1 + (k1.r1) v1, R1 = d1*r1 + (b1.r1) a1.
__global__ __launch_bounds__(64) void prep2_k(
    float* __restrict__ rkv,
    const float* __restrict__ vfirst,
    const float* __restrict__ ywb, const float* __restrict__ yab,
    const float* __restrict__ yvb,
    float* __restrict__ pk,
    const float* __restrict__ w0, const float* __restrict__ a0,
    const float* __restrict__ v0, const float* __restrict__ k_k,
    const float* __restrict__ k_a, const float* __restrict__ amask) {
    int tp = blockIdx.x >> 5;
    int h  = blockIdx.x & 31;
    int n  = threadIdx.x;
    int cc = h * HEAD + n;

    float d[2], a[2], bv[2], k[2], v[2], r[2];
#pragma unroll
    for (int s = 0; s < 2; ++s) {
        int t = 2 * tp + s;
        int idx = t * C_DIM + cc;
        size_t idx6 = (size_t)t * RKV_N + cc;
        float m  = amask[t];
        float rr = rkv[idx6];
        float kv = rkv[idx6 + 2048];
        float vv = rkv[idx6 + 4096];
        float wv = w0[cc] + ywb[idx];
        float wfin = -log1pf(expf(-wv)) - 0.6f;       // -softplus(-x) - 0.6
        float dec  = expf(-expf(wfin));
        float sv   = 1.f / (1.f + expf(-(v0[cc] + yvb[idx])));
        float vnew = fmaf(vfirst[idx] - vv, sv, vv);
        float av   = 1.f / (1.f + expf(-(a0[cc] + yab[idx])));
        float kkp  = kv * k_k[cc];
        float ss = kkp * kkp;
#pragma unroll
        for (int off = 32; off > 0; off >>= 1) ss += __shfl_xor(ss, off);
        float kkn  = kkp / fmaxf(sqrtf(ss), 1e-12f);
        float knew = kv * (1.f + (av - 1.f) * k_a[cc]);
        d[s]  = dec * m + (1.f - m);
        a[s]  = -kkn * m;
        bv[s] = kkn * av * m;
        k[s]  = knew * m;
        v[s]  = vnew * m;
        r[s]  = rr;
        rkv[idx6 + 2048] = knew;   // unmasked, for residual
        rkv[idx6 + 4096] = vnew;   // unmasked, for residual
    }

    // cross-step dot products (64-lane reduces)
    float dba = bv[0] * a[1];   // b1.a2
    float dka = k[0]  * a[1];   // k1.a2
    float dbr = bv[0] * r[0];   // b1.r1
    float dkr = k[0]  * r[0];   // k1.r1
#pragma unroll
    for (int off = 32; off > 0; off >>= 1) {
        dba += __shfl_xor(dba, off);
        dka += __shfl_xor(dka, off);
        dbr += __shfl_xor(dbr, off);
        dkr += __shfl_xor(dkr, off);
    }

    size_t rec = ((size_t)tp * H_N + h) * REC2;
    pk[rec + n]        = a[0];                          // A1
    pk[rec + 64 + n]   = d[0] * a[1];                   // A2
    pk[rec + 128 + n]  = fmaf(dbr, a[0], d[0] * r[0]);  // R1
    pk[rec + 192 + n]  = d[0] * d[1];                   // DD
    pk[rec + 256 + n]  = fmaf(dba, bv[1], d[1] * bv[0]);// B1
    pk[rec + 320 + n]  = bv[1];                         // B2
    pk[rec + 384 + n]  = fmaf(dka, bv[1], d[1] * k[0]); // C1
    pk[rec + 448 + n]  = k[1];                          // C2
    pk[rec + 512 + n]  = r[1];                          // R2
    pk[rec + 576 + n]  = v[0];                          // v1
    pk[rec + 640 + n]  = v[1];                          // v2
    if (n == 0) pk[rec + 704] = dkr;                    // G1 scalar
}

// ---------------- sequential scan v6: DOUBLE-STEP, plain-load ring-4, sched_barrier pins --
// Reverted to R2's compiler-visible plain float4 loads (correctness: SIInsertWaitcnts
// inserts exact counted vmcnt waits from register deps). R2's defect was the Machine-
// Scheduler SINKING the ring loads toward uses (prefetch distance -> 0; VGPR collapsed to
// 156). Fix: sched_barrier(0) phase fences pin [prefetch-issue][compute] per step, so the
// compiler's own wait for slot data lands AFTER the prefetch issue (4-step distance kept).
__global__ __launch_bounds__(64, 1) void scan_k(
    const float* __restrict__ pk, float* __restrict__ out) {
    int b = blockIdx.x;
    int xcd  = b & 7;
    int rest = b >> 3;       // 0..63
    int hi   = rest & 3;
    int g    = rest >> 2;    // 0..15
    int h    = xcd + 8 * hi;

    int lane = threadIdx.x;
    int r = lane >> 4;       // 0..3
    int c = lane & 15;       // 0..15
    int row = g * 4 + r;
    int jb  = c * 4;

    float S0 = 0.f, S1 = 0.f, S2 = 0.f, S3 = 0.f;

    float4 A1R[4], A2R[4], R1R[4], DDR[4], B1R[4], B2R[4], C1R[4], C2R[4], R2R[4];
    float  v1R[4], v2R[4], g1R[4];

    const size_t tstep = (size_t)H_N * REC2;   // 24576 floats per t-pair
    const float* base = pk + (size_t)h * REC2;

#define LOADSLOT(S_, T_) do {                          \
    const float* L_ = base + (size_t)(T_) * tstep;     \
    A1R[S_] = *(const float4*)(L_ + jb);               \
    A2R[S_] = *(const float4*)(L_ + 64 + jb);          \
    R1R[S_] = *(const float4*)(L_ + 128 + jb);         \
    DDR[S_] = *(const float4*)(L_ + 192 + jb);         \
    B1R[S_] = *(const float4*)(L_ + 256 + jb);         \
    B2R[S_] = *(const float4*)(L_ + 320 + jb);         \
    C1R[S_] = *(const float4*)(L_ + 384 + jb);         \
    C2R[S_] = *(const float4*)(L_ + 448 + jb);         \
    R2R[S_] = *(const float4*)(L_ + 512 + jb);         \
    v1R[S_] = L_[576 + row];                           \
    v2R[S_] = L_[640 + row];                           \
    g1R[S_] = L_[704];                                 \
} while (0)

#pragma unroll
    for (int s = 0; s < 4; ++s) LOADSLOT(s, s);
    __builtin_amdgcn_sched_barrier(0);

    int off = h * HEAD;

#pragma unroll 1
    for (int tp0 = 0; tp0 < NPAIR; tp0 += 4) {
#pragma unroll
        for (int s = 0; s < 4; ++s) {
            int tp = tp0 + s;
            // snapshot slot s (pre-update values), then issue its prefetch for tp+4
            float4 A1v = A1R[s], A2v = A2R[s], R1v = R1R[s], DDv = DDR[s];
            float4 B1v = B1R[s], B2v = B2R[s], C1v = C1R[s], C2v = C2R[s];
            float4 R2v = R2R[s];
            float  vv1 = v1R[s], vv2 = v2R[s], gg1 = g1R[s];
            int tn = tp + 4;
            if (tn > NPAIR - 1) tn = NPAIR - 1;
            LOADSLOT(s, tn);
            __builtin_amdgcn_sched_barrier(0);   // loads must be ISSUED before compute

            // three parallel 16-lane reduces on pre-update S
            float pa = fmaf(S0, A1v.x, S1 * A1v.y);
            float qa = fmaf(S2, A1v.z, S3 * A1v.w);
            float pb = fmaf(S0, A2v.x, S1 * A2v.y);
            float qb = fmaf(S2, A2v.z, S3 * A2v.w);
            float pr = fmaf(S0, R1v.x, S1 * R1v.y);
            float qr = fmaf(S2, R1v.z, S3 * R1v.w);
            float sa1 = hex_add(pa + qa);
            float sa2 = hex_add(pb + qb);
            float so1 = hex_add(pr + qr);
            // first output (timestep 2*tp)
            if (c == 0) out[off + row] = fmaf(gg1, vv1, so1);

            // const term: v1*C1 + v2*C2
            float t0c = fmaf(vv1, C1v.x, vv2 * C2v.x);
            float t1c = fmaf(vv1, C1v.y, vv2 * C2v.y);
            float t2c = fmaf(vv1, C1v.z, vv2 * C2v.z);
            float t3c = fmaf(vv1, C1v.w, vv2 * C2v.w);
            // update: S = S*DD + sa1*B1 + sa2*B2 + const
            float z0 = fmaf(sa1, B1v.x, t0c);
            float z1 = fmaf(sa1, B1v.y, t1c);
            float z2 = fmaf(sa1, B1v.z, t2c);
            float z3 = fmaf(sa1, B1v.w, t3c);
            float y0 = fmaf(sa2, B2v.x, z0);
            float y1 = fmaf(sa2, B2v.y, z1);
            float y2 = fmaf(sa2, B2v.z, z2);
            float y3 = fmaf(sa2, B2v.w, z3);
            S0 = fmaf(DDv.x, S0, y0);
            S1 = fmaf(DDv.y, S1, y1);
            S2 = fmaf(DDv.z, S2, y2);
            S3 = fmaf(DDv.w, S3, y3);

            // second output (timestep 2*tp+1) on post-update S
            float o0 = fmaf(S0, R2v.x, S1 * R2v.y);
            float o1 = fmaf(S2, R2v.z, S3 * R2v.w);
            float op = hex_add(o0 + o1);
            if (c == 0) out[off + C_DIM + row] = op;
            off += 2 * C_DIM;
            __builtin_amdgcn_sched_barrier(0);   // keep next step's loads out of this compute
        }
    }
#undef LOADSLOT
}

// ---------------- residual + cast + v_first passthrough ----------------
__global__ __launch_bounds__(64) void resid_k(
    const float* __restrict__ rkv, const float* __restrict__ souts,
    const float* __restrict__ r_k, const float* __restrict__ vfirst,
    __bf16* __restrict__ ob, float* __restrict__ dout) {
    int t = blockIdx.x >> 5;
    int h = blockIdx.x & 31;
    int n = threadIdx.x;
    int cc  = h * HEAD + n;
    int idx = t * C_DIM + cc;
    size_t idx6 = (size_t)t * RKV_N + cc;
    float s = rkv[idx6] * rkv[idx6 + 2048] * r_k[cc];
#pragma unroll
    for (int off = 32; off > 0; off >>= 1) s += __shfl_xor(s, off);
    float ov = souts[idx] + s * rkv[idx6 + 4096];
    ob[idx] = (__bf16)ov;
    dout[BTC + idx] = vfirst[idx];
}

// ---------------- host launcher ----------------
extern "C" void kernel_launch(void* const* d_in, const int* in_sizes, int n_in,
                              void* d_out, int out_size, void* d_ws, size_t ws_size,
                              hipStream_t stream) {
    const float* x      = (const float*)d_in[0];
    const float* vfirst = (const float*)d_in[1];
    const float* amask  = (const float*)d_in[2];
    const float* w0 = (const float*)d_in[3];
    const float* w1 = (const float*)d_in[4];
    const float* w2 = (const float*)d_in[5];
    const float* a0 = (const float*)d_in[6];
    const float* a1 = (const float*)d_in[7];
    const float* a2 = (const float*)d_in[8];
    const float* v0 = (const float*)d_in[9];
    const float* v1 = (const float*)d_in[10];
    const float* v2 = (const float*)d_in[11];
    const float* k_k = (const float*)d_in[12];
    const float* k_a = (const float*)d_in[13];
    const float* r_k = (const float*)d_in[14];
    const float* Wr = (const float*)d_in[15];
    const float* Wk = (const float*)d_in[16];
    const float* Wv = (const float*)d_in[17];
    const float* Wo = (const float*)d_in[18];
    float* dout = (float*)d_out;

    char* wp = (char*)d_ws;
    auto alloc = [&](size_t bytes) -> void* {
        void* p = (void*)wp;
        wp += (bytes + 255) & ~(size_t)255;
        return p;
    };
    __bf16* xb   = (__bf16*)alloc((size_t)BTC * 2);
    __bf16* rkvT = (__bf16*)alloc((size_t)3 * C_DIM * C_DIM * 2);  // WrT|WkT|WvT contiguous
    __bf16* WoT  = (__bf16*)alloc((size_t)C_DIM * C_DIM * 2);
    __bf16* w1T = (__bf16*)alloc((size_t)96 * C_DIM * 2);
    __bf16* a1T = (__bf16*)alloc((size_t)96 * C_DIM * 2);
    __bf16* v1T = (__bf16*)alloc((size_t)64 * C_DIM * 2);
    __bf16* w2T = (__bf16*)alloc((size_t)C_DIM * 96 * 2);
    __bf16* a2T = (__bf16*)alloc((size_t)C_DIM * 96 * 2);
    __bf16* v2T = (__bf16*)alloc((size_t)C_DIM * 64 * 2);
    float*  rkv = (float*)alloc((size_t)T_LEN * RKV_N * 4);        // fused r|k|v output
    float*  hw  = (float*)alloc((size_t)T_LEN * 96 * 4);
    float*  ha  = (float*)alloc((size_t)T_LEN * 96 * 4);
    float*  hv  = (float*)alloc((size_t)T_LEN * 64 * 4);
    __bf16* hwb = (__bf16*)alloc((size_t)T_LEN * 96 * 2);
    __bf16* hab = (__bf16*)alloc((size_t)T_LEN * 96 * 2);
    __bf16* hvb = (__bf16*)alloc((size_t)T_LEN * 64 * 2);
    float*  ywb = (float*)alloc((size_t)BTC * 4);   // LoRA w output
    float*  yab = (float*)alloc((size_t)BTC * 4);   // LoRA a output
    float*  yvb = (float*)alloc((size_t)BTC * 4);   // LoRA v output
    float*  pk  = (float*)alloc((size_t)NPAIR * H_N * REC2 * 4 + 4096);
    float*  souts = (float*)alloc((size_t)BTC * 4);
    __bf16* ob  = (__bf16*)alloc((size_t)BTC * 2);

    // 1) cast x -> bf16
    cast_bf16_k<<<dim3(BTC / 256), 256, 0, stream>>>(x, xb, BTC);

    // 2) transpose+cast all weights (dst = C x R); Wr/Wk/Wv into one contiguous BT
    dim3 tb(32, 8);
    transpose_cast_k<<<dim3(64, 64), tb, 0, stream>>>(Wr, rkvT, C_DIM, C_DIM);
    transpose_cast_k<<<dim3(64, 64), tb, 0, stream>>>(Wk, rkvT + (size_t)C_DIM * C_DIM, C_DIM, C_DIM);
    transpose_cast_k<<<dim3(64, 64), tb, 0, stream>>>(Wv, rkvT + (size_t)2 * C_DIM * C_DIM, C_DIM, C_DIM);
    transpose_cast_k<<<dim3(64, 64), tb, 0, stream>>>(Wo, WoT, C_DIM, C_DIM);
    transpose_cast_k<<<dim3(3, 64), tb, 0, stream>>>(w1, w1T, C_DIM, 96);
    transpose_cast_k<<<dim3(3, 64), tb, 0, stream>>>(a1, a1T, C_DIM, 96);
    transpose_cast_k<<<dim3(2, 64), tb, 0, stream>>>(v1, v1T, C_DIM, 64);
    transpose_cast_k<<<dim3(64, 3), tb, 0, stream>>>(w2, w2T, 96, C_DIM);
    transpose_cast_k<<<dim3(64, 3), tb, 0, stream>>>(a2, a2T, 96, C_DIM);
    transpose_cast_k<<<dim3(64, 2), tb, 0, stream>>>(v2, v2T, 64, C_DIM);

    // 3) fused big GEMM: rkv = xb @ [Wr|Wk|Wv]  (768 blocks = 3/CU)
    gemm_lds_64x128<<<dim3(16, 48), 256, 0, stream>>>(xb, rkvT, rkv, T_LEN, RKV_N, C_DIM);

    // 4) LoRA first stage
    gemm_bt_w16<<<dim3(64, 6), 64, 0, stream>>>(xb, w1T, hw, T_LEN, 96, C_DIM);
    gemm_bt_w16<<<dim3(64, 6), 64, 0, stream>>>(xb, a1T, ha, T_LEN, 96, C_DIM);
    gemm_bt_w16<<<dim3(64, 4), 64, 0, stream>>>(xb, v1T, hv, T_LEN, 64, C_DIM);

    // 5) activations + cast
    tanh_cast_k<<<dim3((T_LEN * 96 + 255) / 256), 256, 0, stream>>>(hw, hwb, T_LEN * 96);
    cast_bf16_k<<<dim3((T_LEN * 96 + 255) / 256), 256, 0, stream>>>(ha, hab, T_LEN * 96);
    cast_bf16_k<<<dim3((T_LEN * 64 + 255) / 256), 256, 0, stream>>>(hv, hvb, T_LEN * 64);

    // 6) LoRA second stage (64x128 tiles, 256 blocks)
    gemm_lds_64x128<<<dim3(16, 16), 256, 0, stream>>>(hwb, w2T, ywb, T_LEN, C_DIM, 96);
    gemm_lds_64x128<<<dim3(16, 16), 256, 0, stream>>>(hab, a2T, yab, T_LEN, C_DIM, 96);
    gemm_lds_64x128<<<dim3(16, 16), 256, 0, stream>>>(hvb, v2T, yvb, T_LEN, C_DIM, 64);

    // 7) prep2: decay, gates, kk-normalize, mask folding, TWO-STEP composition packing
    prep2_k<<<dim3(NPAIR * H_N), 64, 0, stream>>>(rkv, vfirst, ywb, yab, yvb,
                                                  pk, w0, a0, v0, k_k, k_a, amask);

    // 8) sequential scan v6: 512 blocks x 1 wave (2/CU), plain-load ring-4 + sched pins
    scan_k<<<dim3(H_N * 16), 64, 0, stream>>>(pk, souts);

    // 9) residual + cast + v_first passthrough
    resid_k<<<dim3(T_LEN * H_N), 64, 0, stream>>>(rkv, souts, r_k, vfirst, ob, dout);

    // 10) final GEMM: dout[0:BTC] = ob @ Wo
    gemm_lds_64x128<<<dim3(16, 16), 256, 0, stream>>>(ob, WoT, dout, T_LEN, C_DIM, C_DIM);
}

// Round 6
// 475.384 us; speedup vs baseline: 1.4973x; 1.1108x over previous
//
#include <hip/hip_runtime.h>
#include <math.h>

#define T_LEN 1024
#define C_DIM 2048
#define H_N   32
#define HEAD  64
#define BTC   (T_LEN * C_DIM)
#define REC2  832   // packed floats per (t-pair,h): [A1|A2|R1|DD|B1|B2|C1|C2|R2]x64 + vrec[64]x4
#define RKV_N 6144  // fused r|k|v GEMM output width
#define NPAIR (T_LEN / 2)

typedef __attribute__((ext_vector_type(8))) __bf16 bf16x8;
typedef __attribute__((ext_vector_type(4))) float  f32x4;

// ---------------- async global->LDS helper (16B/lane, wave-uniform LDS base) -------------
__device__ __forceinline__ void gll16(const void* g, void* l) {
    __builtin_amdgcn_global_load_lds((const __attribute__((address_space(1))) void*)g,
                                     (__attribute__((address_space(3))) void*)l, 16, 0, 0);
}

// 16-lane reduce, pure DPP: quad xor1, quad xor2, row_half_mirror (8), row_mirror (16)
__device__ __forceinline__ float hex_add(float x) {
    int a = __builtin_amdgcn_mov_dpp(__float_as_int(x), 0xB1, 0xF, 0xF, true);   // quad_perm [1,0,3,2]
    float y = x + __int_as_float(a);
    int b = __builtin_amdgcn_mov_dpp(__float_as_int(y), 0x4E, 0xF, 0xF, true);   // quad_perm [2,3,0,1]
    float z = y + __int_as_float(b);
    int c = __builtin_amdgcn_mov_dpp(__float_as_int(z), 0x141, 0xF, 0xF, true);  // row_half_mirror
    float w = z + __int_as_float(c);
    int d = __builtin_amdgcn_mov_dpp(__float_as_int(w), 0x140, 0xF, 0xF, true);  // row_mirror
    return w + __int_as_float(d);
}

// ---------------- cast x -> bf16 ----------------
__global__ void cast_bf16_k(const float* __restrict__ s, __bf16* __restrict__ d, int n) {
    int i = blockIdx.x * 256 + threadIdx.x;
    if (i < n) d[i] = (__bf16)s[i];
}

// ---------------- fused LoRA-1 activation: tanh on cols [0,96), identity [96,256) --------
__global__ void act_lora1_k(const float* __restrict__ s, __bf16* __restrict__ d) {
    int i = blockIdx.x * 256 + threadIdx.x;
    float v = s[i];
    if ((i & 255) < 96) v = tanhf(v);
    d[i] = (__bf16)v;
}

// ---------------- batched transpose + cast: dst[c*R + r] = (bf16)src[r*C + c] ------------
struct TransBatch {
    const float* s[10];
    __bf16*      d[10];
    int R[10];
    int C[10];
};
__global__ void transpose_batch_k(TransBatch tb) {
    int z = blockIdx.z;
    const float* src = tb.s[z];
    __bf16* dst = tb.d[z];
    int R = tb.R[z], C = tb.C[z];
    int c0 = blockIdx.x * 32, r0 = blockIdx.y * 32;
    if (c0 >= C || r0 >= R) return;           // dims are multiples of 32
    __shared__ float tile[32][33];
    int tx = threadIdx.x, ty = threadIdx.y;
#pragma unroll
    for (int i = 0; i < 32; i += 8)
        tile[ty + i][tx] = src[(size_t)(r0 + ty + i) * C + c0 + tx];
    __syncthreads();
#pragma unroll
    for (int i = 0; i < 32; i += 8)
        dst[(size_t)(c0 + ty + i) * R + r0 + tx] = (__bf16)tile[tx][ty + i];
}

// ---------------- GEMM 64x128 tile, LDS-DMA staging: O = A(MxK) * BT(NxK) ----------------
__global__ __launch_bounds__(256) void gemm_lds_64x128(
    const __bf16* __restrict__ A, const __bf16* __restrict__ BT,
    float* __restrict__ O, int M, int N, int K) {
    __shared__ __bf16 As[64 * 32];
    __shared__ __bf16 Bs[128 * 32];
    int tid  = threadIdx.x;
    int lane = tid & 63;
    int wv   = tid >> 6;
    int m    = lane & 15;
    int q    = lane >> 4;
    int wr   = wv >> 1, wc = wv & 1;
    int row0 = blockIdx.x * 64;
    int col0 = blockIdx.y * 128;

    int srow  = tid >> 2;          // 0..63
    int skoff = (tid & 3) * 8;
    const __bf16* agp = A  + (size_t)(row0 + srow) * K + skoff;
    const __bf16* bgp = BT + (size_t)(col0 + srow) * K + skoff;
    __bf16* alp = As + (size_t)(tid & ~63) * 8;   // wave-uniform base (+ HW lane*16B)
    __bf16* blp = Bs + (size_t)(tid & ~63) * 8;

    f32x4 acc[2][4];
#pragma unroll
    for (int i = 0; i < 2; i++)
#pragma unroll
        for (int j = 0; j < 4; j++) acc[i][j] = {0.f, 0.f, 0.f, 0.f};

    for (int k0 = 0; k0 < K; k0 += 32) {
        gll16(agp + k0, alp);
        gll16(bgp + k0, blp);
        gll16(bgp + (size_t)64 * K + k0, blp + 64 * 32);
        __syncthreads();

        bf16x8 af[2], bfv[4];
#pragma unroll
        for (int i = 0; i < 2; i++)
            af[i] = *(const bf16x8*)&As[(wr * 32 + i * 16 + m) * 32 + q * 8];
#pragma unroll
        for (int j = 0; j < 4; j++)
            bfv[j] = *(const bf16x8*)&Bs[(wc * 64 + j * 16 + m) * 32 + q * 8];
#pragma unroll
        for (int i = 0; i < 2; i++)
#pragma unroll
            for (int j = 0; j < 4; j++)
                acc[i][j] = __builtin_amdgcn_mfma_f32_16x16x32_bf16(af[i], bfv[j], acc[i][j], 0, 0, 0);
        __syncthreads();
    }

#pragma unroll
    for (int i = 0; i < 2; i++) {
        int orow = row0 + wr * 32 + i * 16 + q * 4;
#pragma unroll
        for (int j = 0; j < 4; j++) {
            int ocol = col0 + wc * 64 + j * 16 + m;
#pragma unroll
            for (int t = 0; t < 4; t++)
                O[(size_t)(orow + t) * N + ocol] = acc[i][j][t];
        }
    }
}

// ---------------- fused LoRA-2 GEMM: grid.z selects (A-offset/K/B/O); A has LDA=256 ------
struct Lora2Cfg {
    const __bf16* A[3];   // hallb + col offset
    const __bf16* BT[3];  // w2T / a2T / v2T (N=2048 rows x K)
    float*        O[3];   // ywb / yab / yvb
    int K[3];
};
__global__ __launch_bounds__(256) void gemm_lora2_k(Lora2Cfg cfg) {
    const int LDA = 256, N = C_DIM;
    int z = blockIdx.z;
    const __bf16* A  = cfg.A[z];
    const __bf16* BT = cfg.BT[z];
    float* O = cfg.O[z];
    int K = cfg.K[z];

    __shared__ __bf16 As[64 * 32];
    __shared__ __bf16 Bs[128 * 32];
    int tid  = threadIdx.x;
    int lane = tid & 63;
    int wv   = tid >> 6;
    int m    = lane & 15;
    int q    = lane >> 4;
    int wr   = wv >> 1, wc = wv & 1;
    int row0 = blockIdx.x * 64;
    int col0 = blockIdx.y * 128;

    int srow  = tid >> 2;
    int skoff = (tid & 3) * 8;
    const __bf16* agp = A  + (size_t)(row0 + srow) * LDA + skoff;
    const __bf16* bgp = BT + (size_t)(col0 + srow) * K + skoff;
    __bf16* alp = As + (size_t)(tid & ~63) * 8;
    __bf16* blp = Bs + (size_t)(tid & ~63) * 8;

    f32x4 acc[2][4];
#pragma unroll
    for (int i = 0; i < 2; i++)
#pragma unroll
        for (int j = 0; j < 4; j++) acc[i][j] = {0.f, 0.f, 0.f, 0.f};

    for (int k0 = 0; k0 < K; k0 += 32) {
        gll16(agp + k0, alp);
        gll16(bgp + k0, blp);
        gll16(bgp + (size_t)64 * K + k0, blp + 64 * 32);
        __syncthreads();

        bf16x8 af[2], bfv[4];
#pragma unroll
        for (int i = 0; i < 2; i++)
            af[i] = *(const bf16x8*)&As[(wr * 32 + i * 16 + m) * 32 + q * 8];
#pragma unroll
        for (int j = 0; j < 4; j++)
            bfv[j] = *(const bf16x8*)&Bs[(wc * 64 + j * 16 + m) * 32 + q * 8];
#pragma unroll
        for (int i = 0; i < 2; i++)
#pragma unroll
            for (int j = 0; j < 4; j++)
                acc[i][j] = __builtin_amdgcn_mfma_f32_16x16x32_bf16(af[i], bfv[j], acc[i][j], 0, 0, 0);
        __syncthreads();
    }

#pragma unroll
    for (int i = 0; i < 2; i++) {
        int orow = row0 + wr * 32 + i * 16 + q * 4;
#pragma unroll
        for (int j = 0; j < 4; j++) {
            int ocol = col0 + wc * 64 + j * 16 + m;
#pragma unroll
            for (int t = 0; t < 4; t++)
                O[(size_t)(orow + t) * N + ocol] = acc[i][j][t];
        }
    }
}

// ---------------- small GEMM: one wave per 16x16 tile (fused LoRA stage 1, N=256) --------
__global__ __launch_bounds__(64) void gemm_bt_w16(
    const __bf16* __restrict__ A, const __bf16* __restrict__ BT,
    float* __restrict__ O, int M, int N, int K) {
    int lane = threadIdx.x & 63;
    int m = lane & 15, q = lane >> 4;
    int row0 = blockIdx.x * 16;
    int col0 = blockIdx.y * 16;
    const __bf16* ap = A  + (size_t)(row0 + m) * K + q * 8;
    const __bf16* bp = BT + (size_t)(col0 + m) * K + q * 8;
    f32x4 acc = {0.f,0.f,0.f,0.f};
    for (int k0 = 0; k0 < K; k0 += 32) {
        bf16x8 av = *(const bf16x8*)(ap + k0);
        bf16x8 bv = *(const bf16x8*)(bp + k0);
        acc = __builtin_amdgcn_mfma_f32_16x16x32_bf16(av, bv, acc, 0, 0, 0);
    }
    int orow = row0 + q * 4;
    int ocol = col0 + m;
#pragma unroll
    for (int i = 0; i < 4; i++)
        O[(size_t)(orow + i) * N + ocol] = acc[i];
}

// ---------------- prep2: per t-PAIR, compute gates + compose two recurrence steps --------
// Double step:  S = S*DD + (S.A1) B1 + (S.A2) B2 + v1 C1 + v2 C2
//   DD = d1*d2; A1 = a1; B1 = d2*b1 + (b1.a2) b2; A2 = d1*a2; B2 = b2;
//   C1 = d2*k1 + (k1.a2) b2; C2 = k2.
// out_t   = S_pre.R1 + (k1.r1) v1,  R1 = d1*r1 + (b1.r1) a1
// out_t+1 = S_post.R2
// vrec[row] = {v1, v2, (k1.r1)*v1, 0} — one dwordx4 per scan lane.
__global__ __launch_bounds__(64) void prep2_k(
    float* __restrict__ rkv,
    const float* __restrict__ vfirst,
    const float* __restrict__ ywb, const float* __restrict__ yab,
    const float* __restrict__ yvb,
    float* __restrict__ pk,
    const float* __restrict__ w0, const float* __restrict__ a0,
    const float* __restrict__ v0, const float* __restrict__ k_k,
    const float* __restrict__ k_a, const float* __restrict__ amask) {
    int tp = blockIdx.x >> 5;
    int h  = blockIdx.x & 31;
    int n  = threadIdx.x;
    int cc = h * HEAD + n;

    float d[2], a[2], bv[2], k[2], v[2], r[2];
#pragma unroll
    for (int s = 0; s < 2; ++s) {
        int t = 2 * tp + s;
        int idx = t * C_DIM + cc;
        size_t idx6 = (size_t)t * RKV_N + cc;
        float m  = amask[t];
        float rr = rkv[idx6];
        float kv = rkv[idx6 + 2048];
        float vv = rkv[idx6 + 4096];
        float wv = w0[cc] + ywb[idx];
        float wfin = -log1pf(expf(-wv)) - 0.6f;       // -softplus(-x) - 0.6
        float dec  = expf(-expf(wfin));
        float sv   = 1.f / (1.f + expf(-(v0[cc] + yvb[idx])));
        float vnew = fmaf(vfirst[idx] - vv, sv, vv);
        float av   = 1.f / (1.f + expf(-(a0[cc] + yab[idx])));
        float kkp  = kv * k_k[cc];
        float ss = kkp * kkp;
#pragma unroll
        for (int off = 32; off > 0; off >>= 1) ss += __shfl_xor(ss, off);
        float kkn  = kkp / fmaxf(sqrtf(ss), 1e-12f);
        float knew = kv * (1.f + (av - 1.f) * k_a[cc]);
        d[s]  = dec * m + (1.f - m);
        a[s]  = -kkn * m;
        bv[s] = kkn * av * m;
        k[s]  = knew * m;
        v[s]  = vnew * m;
        r[s]  = rr;
        rkv[idx6 + 2048] = knew;   // unmasked, for residual
        rkv[idx6 + 4096] = vnew;   // unmasked, for residual
    }

    // cross-step dot products (64-lane reduces)
    float dba = bv[0] * a[1];   // b1.a2
    float dka = k[0]  * a[1];   // k1.a2
    float dbr = bv[0] * r[0];   // b1.r1
    float dkr = k[0]  * r[0];   // k1.r1
#pragma unroll
    for (int off = 32; off > 0; off >>= 1) {
        dba += __shfl_xor(dba, off);
        dka += __shfl_xor(dka, off);
        dbr += __shfl_xor(dbr, off);
        dkr += __shfl_xor(dkr, off);
    }

    size_t rec = ((size_t)tp * H_N + h) * REC2;
    pk[rec + n]        = a[0];                          // A1
    pk[rec + 64 + n]   = d[0] * a[1];                   // A2
    pk[rec + 128 + n]  = fmaf(dbr, a[0], d[0] * r[0]);  // R1
    pk[rec + 192 + n]  = d[0] * d[1];                   // DD
    pk[rec + 256 + n]  = fmaf(dba, bv[1], d[1] * bv[0]);// B1
    pk[rec + 320 + n]  = bv[1];                         // B2
    pk[rec + 384 + n]  = fmaf(dka, bv[1], d[1] * k[0]); // C1
    pk[rec + 448 + n]  = k[1];                          // C2
    pk[rec + 512 + n]  = r[1];                          // R2
    float4 vr = {v[0], v[1], dkr * v[0], 0.f};          // vrec[row n]
    *(float4*)&pk[rec + 576 + n * 4] = vr;
}

// ---------------- sequential scan v7: DOUBLE-STEP, plain-load ring-4, 10 loads/step ------
// R5 structure (proven correct) with v1/v2/g1*v1 packed into one vrec dwordx4 (12 -> 10
// VMEM loads per step; retire model says ~44 cy/load at 1 wave/SIMD).
__global__ __launch_bounds__(64, 1) void scan_k(
    const float* __restrict__ pk, float* __restrict__ out) {
    int b = blockIdx.x;
    int xcd  = b & 7;
    int rest = b >> 3;       // 0..63
    int hi   = rest & 3;
    int g    = rest >> 2;    // 0..15
    int h    = xcd + 8 * hi;

    int lane = threadIdx.x;
    int r = lane >> 4;       // 0..3
    int c = lane & 15;       // 0..15
    int row = g * 4 + r;
    int jb  = c * 4;

    float S0 = 0.f, S1 = 0.f, S2 = 0.f, S3 = 0.f;

    float4 A1R[4], A2R[4], R1R[4], DDR[4], B1R[4], B2R[4], C1R[4], C2R[4], R2R[4], VRR[4];

    const size_t tstep = (size_t)H_N * REC2;   // floats per t-pair
    const float* base = pk + (size_t)h * REC2;

#define LOADSLOT(S_, T_) do {                          \
    const float* L_ = base + (size_t)(T_) * tstep;     \
    A1R[S_] = *(const float4*)(L_ + jb);               \
    A2R[S_] = *(const float4*)(L_ + 64 + jb);          \
    R1R[S_] = *(const float4*)(L_ + 128 + jb);         \
    DDR[S_] = *(const float4*)(L_ + 192 + jb);         \
    B1R[S_] = *(const float4*)(L_ + 256 + jb);         \
    B2R[S_] = *(const float4*)(L_ + 320 + jb);         \
    C1R[S_] = *(const float4*)(L_ + 384 + jb);         \
    C2R[S_] = *(const float4*)(L_ + 448 + jb);         \
    R2R[S_] = *(const float4*)(L_ + 512 + jb);         \
    VRR[S_] = *(const float4*)(L_ + 576 + row * 4);    \
} while (0)

#pragma unroll
    for (int s = 0; s < 4; ++s) LOADSLOT(s, s);
    __builtin_amdgcn_sched_barrier(0);

    int off = h * HEAD;

#pragma unroll 1
    for (int tp0 = 0; tp0 < NPAIR; tp0 += 4) {
#pragma unroll
        for (int s = 0; s < 4; ++s) {
            int tp = tp0 + s;
            float4 A1v = A1R[s], A2v = A2R[s], R1v = R1R[s], DDv = DDR[s];
            float4 B1v = B1R[s], B2v = B2R[s], C1v = C1R[s], C2v = C2R[s];
            float4 R2v = R2R[s], vr = VRR[s];
            int tn = tp + 4;
            if (tn > NPAIR - 1) tn = NPAIR - 1;
            LOADSLOT(s, tn);
            __builtin_amdgcn_sched_barrier(0);   // loads issued before compute

            float vv1 = vr.x, vv2 = vr.y;
            // three parallel 16-lane reduces on pre-update S
            float pa = fmaf(S0, A1v.x, S1 * A1v.y);
            float qa = fmaf(S2, A1v.z, S3 * A1v.w);
            float pb = fmaf(S0, A2v.x, S1 * A2v.y);
            float qb = fmaf(S2, A2v.z, S3 * A2v.w);
            float pr = fmaf(S0, R1v.x, S1 * R1v.y);
            float qr = fmaf(S2, R1v.z, S3 * R1v.w);
            float sa1 = hex_add(pa + qa);
            float sa2 = hex_add(pb + qb);
            float so1 = hex_add(pr + qr);
            // first output (timestep 2*tp): so1 + g1*v1 (precomputed in vr.z)
            if (c == 0) out[off + row] = so1 + vr.z;

            // const term: v1*C1 + v2*C2
            float t0c = fmaf(vv1, C1v.x, vv2 * C2v.x);
            float t1c = fmaf(vv1, C1v.y, vv2 * C2v.y);
            float t2c = fmaf(vv1, C1v.z, vv2 * C2v.z);
            float t3c = fmaf(vv1, C1v.w, vv2 * C2v.w);
            // update: S = S*DD + sa1*B1 + sa2*B2 + const
            float z0 = fmaf(sa1, B1v.x, t0c);
            float z1 = fmaf(sa1, B1v.y, t1c);
            float z2 = fmaf(sa1, B1v.z, t2c);
            float z3 = fmaf(sa1, B1v.w, t3c);
            float y0 = fmaf(sa2, B2v.x, z0);
            float y1 = fmaf(sa2, B2v.y, z1);
            float y2 = fmaf(sa2, B2v.z, z2);
            float y3 = fmaf(sa2, B2v.w, z3);
            S0 = fmaf(DDv.x, S0, y0);
            S1 = fmaf(DDv.y, S1, y1);
            S2 = fmaf(DDv.z, S2, y2);
            S3 = fmaf(DDv.w, S3, y3);

            // second output (timestep 2*tp+1) on post-update S
            float o0 = fmaf(S0, R2v.x, S1 * R2v.y);
            float o1 = fmaf(S2, R2v.z, S3 * R2v.w);
            float op = hex_add(o0 + o1);
            if (c == 0) out[off + C_DIM + row] = op;
            off += 2 * C_DIM;
            __builtin_amdgcn_sched_barrier(0);
        }
    }
#undef LOADSLOT
}

// ---------------- residual + cast + v_first passthrough ----------------
__global__ __launch_bounds__(64) void resid_k(
    const float* __restrict__ rkv, const float* __restrict__ souts,
    const float* __restrict__ r_k, const float* __restrict__ vfirst,
    __bf16* __restrict__ ob, float* __restrict__ dout) {
    int t = blockIdx.x >> 5;
    int h = blockIdx.x & 31;
    int n = threadIdx.x;
    int cc  = h * HEAD + n;
    int idx = t * C_DIM + cc;
    size_t idx6 = (size_t)t * RKV_N + cc;
    float s = rkv[idx6] * rkv[idx6 + 2048] * r_k[cc];
#pragma unroll
    for (int off = 32; off > 0; off >>= 1) s += __shfl_xor(s, off);
    float ov = souts[idx] + s * rkv[idx6 + 4096];
    ob[idx] = (__bf16)ov;
    dout[BTC + idx] = vfirst[idx];
}

// ---------------- host launcher ----------------
extern "C" void kernel_launch(void* const* d_in, const int* in_sizes, int n_in,
                              void* d_out, int out_size, void* d_ws, size_t ws_size,
                              hipStream_t stream) {
    const float* x      = (const float*)d_in[0];
    const float* vfirst = (const float*)d_in[1];
    const float* amask  = (const float*)d_in[2];
    const float* w0 = (const float*)d_in[3];
    const float* w1 = (const float*)d_in[4];
    const float* w2 = (const float*)d_in[5];
    const float* a0 = (const float*)d_in[6];
    const float* a1 = (const float*)d_in[7];
    const float* a2 = (const float*)d_in[8];
    const float* v0 = (const float*)d_in[9];
    const float* v1 = (const float*)d_in[10];
    const float* v2 = (const float*)d_in[11];
    const float* k_k = (const float*)d_in[12];
    const float* k_a = (const float*)d_in[13];
    const float* r_k = (const float*)d_in[14];
    const float* Wr = (const float*)d_in[15];
    const float* Wk = (const float*)d_in[16];
    const float* Wv = (const float*)d_in[17];
    const float* Wo = (const float*)d_in[18];
    float* dout = (float*)d_out;

    char* wp = (char*)d_ws;
    auto alloc = [&](size_t bytes) -> void* {
        void* p = (void*)wp;
        wp += (bytes + 255) & ~(size_t)255;
        return p;
    };
    __bf16* xb     = (__bf16*)alloc((size_t)BTC * 2);
    __bf16* rkvT   = (__bf16*)alloc((size_t)3 * C_DIM * C_DIM * 2);  // WrT|WkT|WvT contiguous
    __bf16* WoT    = (__bf16*)alloc((size_t)C_DIM * C_DIM * 2);
    __bf16* lora1T = (__bf16*)alloc((size_t)256 * C_DIM * 2);        // w1T|a1T|v1T contiguous
    __bf16* w2T = (__bf16*)alloc((size_t)C_DIM * 96 * 2);
    __bf16* a2T = (__bf16*)alloc((size_t)C_DIM * 96 * 2);
    __bf16* v2T = (__bf16*)alloc((size_t)C_DIM * 64 * 2);
    float*  rkv = (float*)alloc((size_t)T_LEN * RKV_N * 4);          // fused r|k|v output
    float*  hall  = (float*)alloc((size_t)T_LEN * 256 * 4);          // fused LoRA-1 output
    __bf16* hallb = (__bf16*)alloc((size_t)T_LEN * 256 * 2);
    float*  ywb = (float*)alloc((size_t)BTC * 4);   // LoRA w output
    float*  yab = (float*)alloc((size_t)BTC * 4);   // LoRA a output
    float*  yvb = (float*)alloc((size_t)BTC * 4);   // LoRA v output
    float*  pk  = (float*)alloc((size_t)NPAIR * H_N * REC2 * 4 + 4096);
    float*  souts = (float*)alloc((size_t)BTC * 4);
    __bf16* ob  = (__bf16*)alloc((size_t)BTC * 2);

    // 1) cast x -> bf16
    cast_bf16_k<<<dim3(BTC / 256), 256, 0, stream>>>(x, xb, BTC);

    // 2) ALL weight transposes in one launch
    TransBatch tb;
    tb.s[0] = Wr; tb.d[0] = rkvT;                              tb.R[0] = C_DIM; tb.C[0] = C_DIM;
    tb.s[1] = Wk; tb.d[1] = rkvT + (size_t)C_DIM * C_DIM;      tb.R[1] = C_DIM; tb.C[1] = C_DIM;
    tb.s[2] = Wv; tb.d[2] = rkvT + (size_t)2 * C_DIM * C_DIM;  tb.R[2] = C_DIM; tb.C[2] = C_DIM;
    tb.s[3] = Wo; tb.d[3] = WoT;                               tb.R[3] = C_DIM; tb.C[3] = C_DIM;
    tb.s[4] = w1; tb.d[4] = lora1T;                            tb.R[4] = C_DIM; tb.C[4] = 96;
    tb.s[5] = a1; tb.d[5] = lora1T + (size_t)96 * C_DIM;       tb.R[5] = C_DIM; tb.C[5] = 96;
    tb.s[6] = v1; tb.d[6] = lora1T + (size_t)192 * C_DIM;      tb.R[6] = C_DIM; tb.C[6] = 64;
    tb.s[7] = w2; tb.d[7] = w2T;                               tb.R[7] = 96;    tb.C[7] = C_DIM;
    tb.s[8] = a2; tb.d[8] = a2T;                               tb.R[8] = 96;    tb.C[8] = C_DIM;
    tb.s[9] = v2; tb.d[9] = v2T;                               tb.R[9] = 64;    tb.C[9] = C_DIM;
    transpose_batch_k<<<dim3(64, 64, 10), dim3(32, 8), 0, stream>>>(tb);

    // 3) fused big GEMM: rkv = xb @ [Wr|Wk|Wv]
    gemm_lds_64x128<<<dim3(16, 48), 256, 0, stream>>>(xb, rkvT, rkv, T_LEN, RKV_N, C_DIM);

    // 4) fused LoRA first stage: hall = xb @ [w1|a1|v1]  (N=256)
    gemm_bt_w16<<<dim3(64, 16), 64, 0, stream>>>(xb, lora1T, hall, T_LEN, 256, C_DIM);

    // 5) fused activation + cast (tanh on w-segment only)
    act_lora1_k<<<dim3(T_LEN * 256 / 256), 256, 0, stream>>>(hall, hallb);

    // 6) fused LoRA second stage (grid.z = 3)
    Lora2Cfg lc;
    lc.A[0] = hallb;       lc.BT[0] = w2T; lc.O[0] = ywb; lc.K[0] = 96;
    lc.A[1] = hallb + 96;  lc.BT[1] = a2T; lc.O[1] = yab; lc.K[1] = 96;
    lc.A[2] = hallb + 192; lc.BT[2] = v2T; lc.O[2] = yvb; lc.K[2] = 64;
    gemm_lora2_k<<<dim3(16, 16, 3), 256, 0, stream>>>(lc);

    // 7) prep2: decay, gates, kk-normalize, mask folding, TWO-STEP composition packing
    prep2_k<<<dim3(NPAIR * H_N), 64, 0, stream>>>(rkv, vfirst, ywb, yab, yvb,
                                                  pk, w0, a0, v0, k_k, k_a, amask);

    // 8) sequential scan v7: 512 blocks x 1 wave, ring-4, 10 loads/step
    scan_k<<<dim3(H_N * 16), 64, 0, stream>>>(pk, souts);

    // 9) residual + cast + v_first passthrough
    resid_k<<<dim3(T_LEN * H_N), 64, 0, stream>>>(rkv, souts, r_k, vfirst, ob, dout);

    // 10) final GEMM: dout[0:BTC] = ob @ Wo
    gemm_lds_64x128<<<dim3(16, 16), 256, 0, stream>>>(ob, WoT, dout, T_LEN, C_DIM, C_DIM);
}

// Round 8
// 473.218 us; speedup vs baseline: 1.5042x; 1.0046x over previous
//
#include <hip/hip_runtime.h>
#include <math.h>

#define T_LEN 1024
#define C_DIM 2048
#define H_N   32
#define HEAD  64
#define BTC   (T_LEN * C_DIM)
#define REC2  768   // packed floats per (t-pair,h): [A1|A2|R1|DD|B1|B2|C1|C2|R2]x64 + vrec3[64]
#define RKV_N 6144  // fused r|k|v GEMM output width
#define NPAIR (T_LEN / 2)

typedef __attribute__((ext_vector_type(8))) __bf16 bf16x8;
typedef __attribute__((ext_vector_type(4))) float  f32x4;

// ---------------- async global->LDS helper (16B/lane, wave-uniform LDS base) -------------
__device__ __forceinline__ void gll16(const void* g, void* l) {
    __builtin_amdgcn_global_load_lds((const __attribute__((address_space(1))) void*)g,
                                     (__attribute__((address_space(3))) void*)l, 16, 0, 0);
}

// 16-lane reduce, pure DPP: quad xor1, quad xor2, row_half_mirror (8), row_mirror (16)
__device__ __forceinline__ float hex_add(float x) {
    int a = __builtin_amdgcn_mov_dpp(__float_as_int(x), 0xB1, 0xF, 0xF, true);   // quad_perm [1,0,3,2]
    float y = x + __int_as_float(a);
    int b = __builtin_amdgcn_mov_dpp(__float_as_int(y), 0x4E, 0xF, 0xF, true);   // quad_perm [2,3,0,1]
    float z = y + __int_as_float(b);
    int c = __builtin_amdgcn_mov_dpp(__float_as_int(z), 0x141, 0xF, 0xF, true);  // row_half_mirror
    float w = z + __int_as_float(c);
    int d = __builtin_amdgcn_mov_dpp(__float_as_int(w), 0x140, 0xF, 0xF, true);  // row_mirror
    return w + __int_as_float(d);
}

// ---------------- cast x -> bf16 ----------------
__global__ void cast_bf16_k(const float* __restrict__ s, __bf16* __restrict__ d, int n) {
    int i = blockIdx.x * 256 + threadIdx.x;
    if (i < n) d[i] = (__bf16)s[i];
}

// ---------------- fused LoRA-1 activation: tanh on cols [0,96), identity [96,256) --------
__global__ void act_lora1_k(const float* __restrict__ s, __bf16* __restrict__ d) {
    int i = blockIdx.x * 256 + threadIdx.x;
    float v = s[i];
    if ((i & 255) < 96) v = tanhf(v);
    d[i] = (__bf16)v;
}

// ---------------- batched transpose + cast: dst[c*R + r] = (bf16)src[r*C + c] ------------
struct TransBatch {
    const float* s[10];
    __bf16*      d[10];
    int R[10];
    int C[10];
};
__global__ void transpose_batch_k(TransBatch tb) {
    int z = blockIdx.z;
    const float* src = tb.s[z];
    __bf16* dst = tb.d[z];
    int R = tb.R[z], C = tb.C[z];
    int c0 = blockIdx.x * 32, r0 = blockIdx.y * 32;
    if (c0 >= C || r0 >= R) return;           // dims are multiples of 32
    __shared__ float tile[32][33];
    int tx = threadIdx.x, ty = threadIdx.y;
#pragma unroll
    for (int i = 0; i < 32; i += 8)
        tile[ty + i][tx] = src[(size_t)(r0 + ty + i) * C + c0 + tx];
    __syncthreads();
#pragma unroll
    for (int i = 0; i < 32; i += 8)
        dst[(size_t)(c0 + ty + i) * R + r0 + tx] = (__bf16)tile[tx][ty + i];
}

// ---------------- GEMM 64x128 tile, LDS-DMA staging: O = A(MxK) * BT(NxK) ----------------
__global__ __launch_bounds__(256) void gemm_lds_64x128(
    const __bf16* __restrict__ A, const __bf16* __restrict__ BT,
    float* __restrict__ O, int M, int N, int K) {
    __shared__ __bf16 As[64 * 32];
    __shared__ __bf16 Bs[128 * 32];
    int tid  = threadIdx.x;
    int lane = tid & 63;
    int wv   = tid >> 6;
    int m    = lane & 15;
    int q    = lane >> 4;
    int wr   = wv >> 1, wc = wv & 1;
    int row0 = blockIdx.x * 64;
    int col0 = blockIdx.y * 128;

    int srow  = tid >> 2;          // 0..63
    int skoff = (tid & 3) * 8;
    const __bf16* agp = A  + (size_t)(row0 + srow) * K + skoff;
    const __bf16* bgp = BT + (size_t)(col0 + srow) * K + skoff;
    __bf16* alp = As + (size_t)(tid & ~63) * 8;   // wave-uniform base (+ HW lane*16B)
    __bf16* blp = Bs + (size_t)(tid & ~63) * 8;

    f32x4 acc[2][4];
#pragma unroll
    for (int i = 0; i < 2; i++)
#pragma unroll
        for (int j = 0; j < 4; j++) acc[i][j] = {0.f, 0.f, 0.f, 0.f};

    for (int k0 = 0; k0 < K; k0 += 32) {
        gll16(agp + k0, alp);
        gll16(bgp + k0, blp);
        gll16(bgp + (size_t)64 * K + k0, blp + 64 * 32);
        __syncthreads();

        bf16x8 af[2], bfv[4];
#pragma unroll
        for (int i = 0; i < 2; i++)
            af[i] = *(const bf16x8*)&As[(wr * 32 + i * 16 + m) * 32 + q * 8];
#pragma unroll
        for (int j = 0; j < 4; j++)
            bfv[j] = *(const bf16x8*)&Bs[(wc * 64 + j * 16 + m) * 32 + q * 8];
#pragma unroll
        for (int i = 0; i < 2; i++)
#pragma unroll
            for (int j = 0; j < 4; j++)
                acc[i][j] = __builtin_amdgcn_mfma_f32_16x16x32_bf16(af[i], bfv[j], acc[i][j], 0, 0, 0);
        __syncthreads();
    }

#pragma unroll
    for (int i = 0; i < 2; i++) {
        int orow = row0 + wr * 32 + i * 16 + q * 4;
#pragma unroll
        for (int j = 0; j < 4; j++) {
            int ocol = col0 + wc * 64 + j * 16 + m;
#pragma unroll
            for (int t = 0; t < 4; t++)
                O[(size_t)(orow + t) * N + ocol] = acc[i][j][t];
        }
    }
}

// ---------------- GEMM 128x128 tile, LDS-DMA staging (big rkv GEMM) ----------------------
// 4 waves; wave wv computes rows [wv*32, wv*32+32) x all 128 cols. 4 DMA + 16 MFMA +
// 10 ds_read per K-iter (2x the MFMA:staging ratio of the 64x128 tile).
__global__ __launch_bounds__(256) void gemm_lds_128x128(
    const __bf16* __restrict__ A, const __bf16* __restrict__ BT,
    float* __restrict__ O, int M, int N, int K) {
    __shared__ __bf16 As[128 * 32];
    __shared__ __bf16 Bs[128 * 32];
    int tid  = threadIdx.x;
    int lane = tid & 63;
    int wv   = tid >> 6;          // 0..3 row strip
    int m    = lane & 15;
    int q    = lane >> 4;
    int row0 = blockIdx.x * 128;
    int col0 = blockIdx.y * 128;

    int srow  = tid >> 2;          // 0..63
    int skoff = (tid & 3) * 8;
    const __bf16* agp = A  + (size_t)(row0 + srow) * K + skoff;
    const __bf16* bgp = BT + (size_t)(col0 + srow) * K + skoff;
    __bf16* alp = As + (size_t)(tid & ~63) * 8;
    __bf16* blp = Bs + (size_t)(tid & ~63) * 8;

    f32x4 acc[2][8];
#pragma unroll
    for (int i = 0; i < 2; i++)
#pragma unroll
        for (int j = 0; j < 8; j++) acc[i][j] = {0.f, 0.f, 0.f, 0.f};

    for (int k0 = 0; k0 < K; k0 += 32) {
        gll16(agp + k0, alp);
        gll16(agp + (size_t)64 * K + k0, alp + 64 * 32);
        gll16(bgp + k0, blp);
        gll16(bgp + (size_t)64 * K + k0, blp + 64 * 32);
        __syncthreads();

        bf16x8 af[2], bfv[8];
#pragma unroll
        for (int i = 0; i < 2; i++)
            af[i] = *(const bf16x8*)&As[(wv * 32 + i * 16 + m) * 32 + q * 8];
#pragma unroll
        for (int j = 0; j < 8; j++)
            bfv[j] = *(const bf16x8*)&Bs[(j * 16 + m) * 32 + q * 8];
#pragma unroll
        for (int i = 0; i < 2; i++)
#pragma unroll
            for (int j = 0; j < 8; j++)
                acc[i][j] = __builtin_amdgcn_mfma_f32_16x16x32_bf16(af[i], bfv[j], acc[i][j], 0, 0, 0);
        __syncthreads();
    }

#pragma unroll
    for (int i = 0; i < 2; i++) {
        int orow = row0 + wv * 32 + i * 16 + q * 4;
#pragma unroll
        for (int j = 0; j < 8; j++) {
            int ocol = col0 + j * 16 + m;
#pragma unroll
            for (int t = 0; t < 4; t++)
                O[(size_t)(orow + t) * N + ocol] = acc[i][j][t];
        }
    }
}

// ---------------- fused LoRA-2 GEMM: grid.z selects (A-offset/K/B/O); A has LDA=256 ------
struct Lora2Cfg {
    const __bf16* A[3];   // hallb + col offset
    const __bf16* BT[3];  // w2T / a2T / v2T (N=2048 rows x K)
    float*        O[3];   // ywb / yab / yvb
    int K[3];
};
__global__ __launch_bounds__(256) void gemm_lora2_k(Lora2Cfg cfg) {
    const int LDA = 256, N = C_DIM;
    int z = blockIdx.z;
    const __bf16* A  = cfg.A[z];
    const __bf16* BT = cfg.BT[z];
    float* O = cfg.O[z];
    int K = cfg.K[z];

    __shared__ __bf16 As[64 * 32];
    __shared__ __bf16 Bs[128 * 32];
    int tid  = threadIdx.x;
    int lane = tid & 63;
    int wv   = tid >> 6;
    int m    = lane & 15;
    int q    = lane >> 4;
    int wr   = wv >> 1, wc = wv & 1;
    int row0 = blockIdx.x * 64;
    int col0 = blockIdx.y * 128;

    int srow  = tid >> 2;
    int skoff = (tid & 3) * 8;
    const __bf16* agp = A  + (size_t)(row0 + srow) * LDA + skoff;
    const __bf16* bgp = BT + (size_t)(col0 + srow) * K + skoff;
    __bf16* alp = As + (size_t)(tid & ~63) * 8;
    __bf16* blp = Bs + (size_t)(tid & ~63) * 8;

    f32x4 acc[2][4];
#pragma unroll
    for (int i = 0; i < 2; i++)
#pragma unroll
        for (int j = 0; j < 4; j++) acc[i][j] = {0.f, 0.f, 0.f, 0.f};

    for (int k0 = 0; k0 < K; k0 += 32) {
        gll16(agp + k0, alp);
        gll16(bgp + k0, blp);
        gll16(bgp + (size_t)64 * K + k0, blp + 64 * 32);
        __syncthreads();

        bf16x8 af[2], bfv[4];
#pragma unroll
        for (int i = 0; i < 2; i++)
            af[i] = *(const bf16x8*)&As[(wr * 32 + i * 16 + m) * 32 + q * 8];
#pragma unroll
        for (int j = 0; j < 4; j++)
            bfv[j] = *(const bf16x8*)&Bs[(wc * 64 + j * 16 + m) * 32 + q * 8];
#pragma unroll
        for (int i = 0; i < 2; i++)
#pragma unroll
            for (int j = 0; j < 4; j++)
                acc[i][j] = __builtin_amdgcn_mfma_f32_16x16x32_bf16(af[i], bfv[j], acc[i][j], 0, 0, 0);
        __syncthreads();
    }

#pragma unroll
    for (int i = 0; i < 2; i++) {
        int orow = row0 + wr * 32 + i * 16 + q * 4;
#pragma unroll
        for (int j = 0; j < 4; j++) {
            int ocol = col0 + wc * 64 + j * 16 + m;
#pragma unroll
            for (int t = 0; t < 4; t++)
                O[(size_t)(orow + t) * N + ocol] = acc[i][j][t];
        }
    }
}

// ---------------- small GEMM: one wave per 16x16 tile (fused LoRA stage 1, N=256) --------
__global__ __launch_bounds__(64) void gemm_bt_w16(
    const __bf16* __restrict__ A, const __bf16* __restrict__ BT,
    float* __restrict__ O, int M, int N, int K) {
    int lane = threadIdx.x & 63;
    int m = lane & 15, q = lane >> 4;
    int row0 = blockIdx.x * 16;
    int col0 = blockIdx.y * 16;
    const __bf16* ap = A  + (size_t)(row0 + m) * K + q * 8;
    const __bf16* bp = BT + (size_t)(col0 + m) * K + q * 8;
    f32x4 acc = {0.f,0.f,0.f,0.f};
    for (int k0 = 0; k0 < K; k0 += 32) {
        bf16x8 av = *(const bf16x8*)(ap + k0);
        bf16x8 bv = *(const bf16x8*)(bp + k0);
        acc = __builtin_amdgcn_mfma_f32_16x16x32_bf16(av, bv, acc, 0, 0, 0);
    }
    int orow = row0 + q * 4;
    int ocol = col0 + m;
#pragma unroll
    for (int i = 0; i < 4; i++)
        O[(size_t)(orow + i) * N + ocol] = acc[i];
}

// ---------------- prep2: per t-PAIR, compute gates + compose two recurrence steps --------
// Double step:  S = S*DD + (S.A1) B1 + (S.A2) B2 + v1 C1 + v2 C2
//   DD = d1*d2; A1 = a1; B1 = d2*b1 + (b1.a2) b2; A2 = d1*a2; B2 = b2;
//   C1 = d2*k1 + (k1.a2) b2; C2 = k2.
// out_t   = S_pre.R1 + (k1.r1) v1,  R1 = d1*r1 + (b1.r1) a1
// out_t+1 = S_post.R2
// vrec3[row] = {v1, v2, (k1.r1)*v1} — one dwordx3 per scan lane; fits REC2=768 exactly.
__global__ __launch_bounds__(64) void prep2_k(
    float* __restrict__ rkv,
    const float* __restrict__ vfirst,
    const float* __restrict__ ywb, const float* __restrict__ yab,
    const float* __restrict__ yvb,
    float* __restrict__ pk,
    const float* __restrict__ w0, const float* __restrict__ a0,
    const float* __restrict__ v0, const float* __restrict__ k_k,
    const float* __restrict__ k_a, const float* __restrict__ amask) {
    int tp = blockIdx.x >> 5;
    int h  = blockIdx.x & 31;
    int n  = threadIdx.x;
    int cc = h * HEAD + n;

    float d[2], a[2], bv[2], k[2], v[2], r[2];
#pragma unroll
    for (int s = 0; s < 2; ++s) {
        int t = 2 * tp + s;
        int idx = t * C_DIM + cc;
        size_t idx6 = (size_t)t * RKV_N + cc;
        float m  = amask[t];
        float rr = rkv[idx6];
        float kv = rkv[idx6 + 2048];
        float vv = rkv[idx6 + 4096];
        float wv = w0[cc] + ywb[idx];
        float wfin = -log1pf(expf(-wv)) - 0.6f;       // -softplus(-x) - 0.6
        float dec  = expf(-expf(wfin));
        float sv   = 1.f / (1.f + expf(-(v0[cc] + yvb[idx])));
        float vnew = fmaf(vfirst[idx] - vv, sv, vv);
        float av   = 1.f / (1.f + expf(-(a0[cc] + yab[idx])));
        float kkp  = kv * k_k[cc];
        float ss = kkp * kkp;
#pragma unroll
        for (int off = 32; off > 0; off >>= 1) ss += __shfl_xor(ss, off);
        float kkn  = kkp / fmaxf(sqrtf(ss), 1e-12f);
        float knew = kv * (1.f + (av - 1.f) * k_a[cc]);
        d[s]  = dec * m + (1.f - m);
        a[s]  = -kkn * m;
        bv[s] = kkn * av * m;
        k[s]  = knew * m;
        v[s]  = vnew * m;
        r[s]  = rr;
        rkv[idx6 + 2048] = knew;   // unmasked, for residual
        rkv[idx6 + 4096] = vnew;   // unmasked, for residual
    }

    // cross-step dot products (64-lane reduces)
    float dba = bv[0] * a[1];   // b1.a2
    float dka = k[0]  * a[1];   // k1.a2
    float dbr = bv[0] * r[0];   // b1.r1
    float dkr = k[0]  * r[0];   // k1.r1
#pragma unroll
    for (int off = 32; off > 0; off >>= 1) {
        dba += __shfl_xor(dba, off);
        dka += __shfl_xor(dka, off);
        dbr += __shfl_xor(dbr, off);
        dkr += __shfl_xor(dkr, off);
    }

    size_t rec = ((size_t)tp * H_N + h) * REC2;
    pk[rec + n]        = a[0];                          // A1
    pk[rec + 64 + n]   = d[0] * a[1];                   // A2
    pk[rec + 128 + n]  = fmaf(dbr, a[0], d[0] * r[0]);  // R1
    pk[rec + 192 + n]  = d[0] * d[1];                   // DD
    pk[rec + 256 + n]  = fmaf(dba, bv[1], d[1] * bv[0]);// B1
    pk[rec + 320 + n]  = bv[1];                         // B2
    pk[rec + 384 + n]  = fmaf(dka, bv[1], d[1] * k[0]); // C1
    pk[rec + 448 + n]  = k[1];                          // C2
    pk[rec + 512 + n]  = r[1];                          // R2
    pk[rec + 576 + n * 3]     = v[0];                   // vrec3
    pk[rec + 576 + n * 3 + 1] = v[1];
    pk[rec + 576 + n * 3 + 2] = dkr * v[0];
}

// ---------------- sequential scan v9: R5's proven structure, 10 loads/step (vrec3) -------
// 512 single-wave blocks (2/CU). Plain compiler-visible loads (SIInsertWaitcnts owns the
// waits -> always correct); ring-4 loop-carried registers; sched_barrier(0) phase pins.
__global__ __launch_bounds__(64, 1) void scan_k(
    const float* __restrict__ pk, float* __restrict__ out) {
    int b = blockIdx.x;
    int xcd  = b & 7;
    int rest = b >> 3;       // 0..63
    int hi   = rest & 3;
    int g    = rest >> 2;    // 0..15
    int h    = xcd + 8 * hi;

    int lane = threadIdx.x;
    int r = lane >> 4;       // 0..3
    int c = lane & 15;       // 0..15
    int row = g * 4 + r;
    int jb  = c * 4;
    int row3 = row * 3;

    float S0 = 0.f, S1 = 0.f, S2 = 0.f, S3 = 0.f;

    float4 A1R[4], A2R[4], R1R[4], DDR[4], B1R[4], B2R[4], C1R[4], C2R[4], R2R[4];
    float3 VRR[4];

    const size_t tstep = (size_t)H_N * REC2;   // 24576 floats per t-pair
    const float* base = pk + (size_t)h * REC2;

#define LOADSLOT(S_, T_) do {                          \
    const float* L_ = base + (size_t)(T_) * tstep;     \
    A1R[S_] = *(const float4*)(L_ + jb);               \
    A2R[S_] = *(const float4*)(L_ + 64 + jb);          \
    R1R[S_] = *(const float4*)(L_ + 128 + jb);         \
    DDR[S_] = *(const float4*)(L_ + 192 + jb);         \
    B1R[S_] = *(const float4*)(L_ + 256 + jb);         \
    B2R[S_] = *(const float4*)(L_ + 320 + jb);         \
    C1R[S_] = *(const float4*)(L_ + 384 + jb);         \
    C2R[S_] = *(const float4*)(L_ + 448 + jb);         \
    R2R[S_] = *(const float4*)(L_ + 512 + jb);         \
    VRR[S_] = *(const float3*)(L_ + 576 + row3);       \
} while (0)

#pragma unroll
    for (int s = 0; s < 4; ++s) LOADSLOT(s, s);
    __builtin_amdgcn_sched_barrier(0);

    int off = h * HEAD;

#pragma unroll 1
    for (int tp0 = 0; tp0 < NPAIR; tp0 += 4) {
#pragma unroll
        for (int s = 0; s < 4; ++s) {
            int tp = tp0 + s;
            float4 A1v = A1R[s], A2v = A2R[s], R1v = R1R[s], DDv = DDR[s];
            float4 B1v = B1R[s], B2v = B2R[s], C1v = C1R[s], C2v = C2R[s];
            float4 R2v = R2R[s];
            float3 vr = VRR[s];
            int tn = tp + 4;
            if (tn > NPAIR - 1) tn = NPAIR - 1;
            LOADSLOT(s, tn);
            __builtin_amdgcn_sched_barrier(0);   // loads issued before compute

            float vv1 = vr.x, vv2 = vr.y;
            // three parallel 16-lane reduces on pre-update S
            float pa = fmaf(S0, A1v.x, S1 * A1v.y);
            float qa = fmaf(S2, A1v.z, S3 * A1v.w);
            float pb = fmaf(S0, A2v.x, S1 * A2v.y);
            float qb = fmaf(S2, A2v.z, S3 * A2v.w);
            float pr = fmaf(S0, R1v.x, S1 * R1v.y);
            float qr = fmaf(S2, R1v.z, S3 * R1v.w);
            float sa1 = hex_add(pa + qa);
            float sa2 = hex_add(pb + qb);
            float so1 = hex_add(pr + qr);
            // first output (timestep 2*tp): so1 + (k1.r1)*v1 (precomputed in vr.z)
            if (c == 0) out[off + row] = so1 + vr.z;

            // const term: v1*C1 + v2*C2
            float t0c = fmaf(vv1, C1v.x, vv2 * C2v.x);
            float t1c = fmaf(vv1, C1v.y, vv2 * C2v.y);
            float t2c = fmaf(vv1, C1v.z, vv2 * C2v.z);
            float t3c = fmaf(vv1, C1v.w, vv2 * C2v.w);
            // update: S = S*DD + sa1*B1 + sa2*B2 + const
            float z0 = fmaf(sa1, B1v.x, t0c);
            float z1 = fmaf(sa1, B1v.y, t1c);
            float z2 = fmaf(sa1, B1v.z, t2c);
            float z3 = fmaf(sa1, B1v.w, t3c);
            float y0 = fmaf(sa2, B2v.x, z0);
            float y1 = fmaf(sa2, B2v.y, z1);
            float y2 = fmaf(sa2, B2v.z, z2);
            float y3 = fmaf(sa2, B2v.w, z3);
            S0 = fmaf(DDv.x, S0, y0);
            S1 = fmaf(DDv.y, S1, y1);
            S2 = fmaf(DDv.z, S2, y2);
            S3 = fmaf(DDv.w, S3, y3);

            // second output (timestep 2*tp+1) on post-update S
            float o0 = fmaf(S0, R2v.x, S1 * R2v.y);
            float o1 = fmaf(S2, R2v.z, S3 * R2v.w);
            float op = hex_add(o0 + o1);
            if (c == 0) out[off + C_DIM + row] = op;
            off += 2 * C_DIM;
            __builtin_amdgcn_sched_barrier(0);
        }
    }
#undef LOADSLOT
}

// ---------------- residual + cast + v_first passthrough ----------------
__global__ __launch_bounds__(64) void resid_k(
    const float* __restrict__ rkv, const float* __restrict__ souts,
    const float* __restrict__ r_k, const float* __restrict__ vfirst,
    __bf16* __restrict__ ob, float* __restrict__ dout) {
    int t = blockIdx.x >> 5;
    int h = blockIdx.x & 31;
    int n = threadIdx.x;
    int cc  = h * HEAD + n;
    int idx = t * C_DIM + cc;
    size_t idx6 = (size_t)t * RKV_N + cc;
    float s = rkv[idx6] * rkv[idx6 + 2048] * r_k[cc];
#pragma unroll
    for (int off = 32; off > 0; off >>= 1) s += __shfl_xor(s, off);
    float ov = souts[idx] + s * rkv[idx6 + 4096];
    ob[idx] = (__bf16)ov;
    dout[BTC + idx] = vfirst[idx];
}

// ---------------- host launcher ----------------
extern "C" void kernel_launch(void* const* d_in, const int* in_sizes, int n_in,
                              void* d_out, int out_size, void* d_ws, size_t ws_size,
                              hipStream_t stream) {
    const float* x      = (const float*)d_in[0];
    const float* vfirst = (const float*)d_in[1];
    const float* amask  = (const float*)d_in[2];
    const float* w0 = (const float*)d_in[3];
    const float* w1 = (const float*)d_in[4];
    const float* w2 = (const float*)d_in[5];
    const float* a0 = (const float*)d_in[6];
    const float* a1 = (const float*)d_in[7];
    const float* a2 = (const float*)d_in[8];
    const float* v0 = (const float*)d_in[9];
    const float* v1 = (const float*)d_in[10];
    const float* v2 = (const float*)d_in[11];
    const float* k_k = (const float*)d_in[12];
    const float* k_a = (const float*)d_in[13];
    const float* r_k = (const float*)d_in[14];
    const float* Wr = (const float*)d_in[15];
    const float* Wk = (const float*)d_in[16];
    const float* Wv = (const float*)d_in[17];
    const float* Wo = (const float*)d_in[18];
    float* dout = (float*)d_out;

    char* wp = (char*)d_ws;
    auto alloc = [&](size_t bytes) -> void* {
        void* p = (void*)wp;
        wp += (bytes + 255) & ~(size_t)255;
        return p;
    };
    __bf16* xb     = (__bf16*)alloc((size_t)BTC * 2);
    __bf16* rkvT   = (__bf16*)alloc((size_t)3 * C_DIM * C_DIM * 2);  // WrT|WkT|WvT contiguous
    __bf16* WoT    = (__bf16*)alloc((size_t)C_DIM * C_DIM * 2);
    __bf16* lora1T = (__bf16*)alloc((size_t)256 * C_DIM * 2);        // w1T|a1T|v1T contiguous
    __bf16* w2T = (__bf16*)alloc((size_t)C_DIM * 96 * 2);
    __bf16* a2T = (__bf16*)alloc((size_t)C_DIM * 96 * 2);
    __bf16* v2T = (__bf16*)alloc((size_t)C_DIM * 64 * 2);
    float*  rkv = (float*)alloc((size_t)T_LEN * RKV_N * 4);          // fused r|k|v output
    float*  hall  = (float*)alloc((size_t)T_LEN * 256 * 4);          // fused LoRA-1 output
    __bf16* hallb = (__bf16*)alloc((size_t)T_LEN * 256 * 2);
    float*  ywb = (float*)alloc((size_t)BTC * 4);   // LoRA w output
    float*  yab = (float*)alloc((size_t)BTC * 4);   // LoRA a output
    float*  yvb = (float*)alloc((size_t)BTC * 4);   // LoRA v output
    float*  pk  = (float*)alloc((size_t)NPAIR * H_N * REC2 * 4 + 4096);
    float*  souts = (float*)alloc((size_t)BTC * 4);
    __bf16* ob  = (__bf16*)alloc((size_t)BTC * 2);

    // 1) cast x -> bf16
    cast_bf16_k<<<dim3(BTC / 256), 256, 0, stream>>>(x, xb, BTC);

    // 2) ALL weight transposes in one launch
    TransBatch tb;
    tb.s[0] = Wr; tb.d[0] = rkvT;                              tb.R[0] = C_DIM; tb.C[0] = C_DIM;
    tb.s[1] = Wk; tb.d[1] = rkvT + (size_t)C_DIM * C_DIM;      tb.R[1] = C_DIM; tb.C[1] = C_DIM;
    tb.s[2] = Wv; tb.d[2] = rkvT + (size_t)2 * C_DIM * C_DIM;  tb.R[2] = C_DIM; tb.C[2] = C_DIM;
    tb.s[3] = Wo; tb.d[3] = WoT;                               tb.R[3] = C_DIM; tb.C[3] = C_DIM;
    tb.s[4] = w1; tb.d[4] = lora1T;                            tb.R[4] = C_DIM; tb.C[4] = 96;
    tb.s[5] = a1; tb.d[5] = lora1T + (size_t)96 * C_DIM;       tb.R[5] = C_DIM; tb.C[5] = 96;
    tb.s[6] = v1; tb.d[6] = lora1T + (size_t)192 * C_DIM;      tb.R[6] = C_DIM; tb.C[6] = 64;
    tb.s[7] = w2; tb.d[7] = w2T;                               tb.R[7] = 96;    tb.C[7] = C_DIM;
    tb.s[8] = a2; tb.d[8] = a2T;                               tb.R[8] = 96;    tb.C[8] = C_DIM;
    tb.s[9] = v2; tb.d[9] = v2T;                               tb.R[9] = 64;    tb.C[9] = C_DIM;
    transpose_batch_k<<<dim3(64, 64, 10), dim3(32, 8), 0, stream>>>(tb);

    // 3) fused big GEMM: rkv = xb @ [Wr|Wk|Wv]  (128x128 tiles, 384 blocks)
    gemm_lds_128x128<<<dim3(8, 48), 256, 0, stream>>>(xb, rkvT, rkv, T_LEN, RKV_N, C_DIM);

    // 4) fused LoRA first stage: hall = xb @ [w1|a1|v1]  (N=256)
    gemm_bt_w16<<<dim3(64, 16), 64, 0, stream>>>(xb, lora1T, hall, T_LEN, 256, C_DIM);

    // 5) fused activation + cast (tanh on w-segment only)
    act_lora1_k<<<dim3(T_LEN * 256 / 256), 256, 0, stream>>>(hall, hallb);

    // 6) fused LoRA second stage (grid.z = 3)
    Lora2Cfg lc;
    lc.A[0] = hallb;       lc.BT[0] = w2T; lc.O[0] = ywb; lc.K[0] = 96;
    lc.A[1] = hallb + 96;  lc.BT[1] = a2T; lc.O[1] = yab; lc.K[1] = 96;
    lc.A[2] = hallb + 192; lc.BT[2] = v2T; lc.O[2] = yvb; lc.K[2] = 64;
    gemm_lora2_k<<<dim3(16, 16, 3), 256, 0, stream>>>(lc);

    // 7) prep2: decay, gates, kk-normalize, mask folding, TWO-STEP composition packing
    prep2_k<<<dim3(NPAIR * H_N), 64, 0, stream>>>(rkv, vfirst, ywb, yab, yvb,
                                                  pk, w0, a0, v0, k_k, k_a, amask);

    // 8) sequential scan v9: 512 blocks x 1 wave, ring-4, 10 loads/step (vrec3)
    scan_k<<<dim3(H_N * 16), 64, 0, stream>>>(pk, souts);

    // 9) residual + cast + v_first passthrough
    resid_k<<<dim3(T_LEN * H_N), 64, 0, stream>>>(rkv, souts, r_k, vfirst, ob, dout);

    // 10) final GEMM: dout[0:BTC] = ob @ Wo
    gemm_lds_64x128<<<dim3(16, 16), 256, 0, stream>>>(ob, WoT, dout, T_LEN, C_DIM, C_DIM);
}